// Round 1
// baseline (784.670 us; speedup 1.0000x reference)
//
#include <hip/hip_runtime.h>
#include <hip/hip_bf16.h>
#include <cstdint>
#include <cstddef>

typedef __bf16 bf16;
typedef __bf16 v8bf  __attribute__((ext_vector_type(8)));
typedef float  f32x4 __attribute__((ext_vector_type(4)));
typedef int    i32x4 __attribute__((ext_vector_type(4)));

// ---------------------------------------------------------------- async copy
__device__ __forceinline__ void async16(bf16* lds, const bf16* g) {
  __builtin_amdgcn_global_load_lds(
      (const __attribute__((address_space(1))) unsigned int*)g,
      (__attribute__((address_space(3))) unsigned int*)lds, 16, 0, 0);
}

// ---------------------------------------------------------------- pairs table
// pairs[k] = (r<<16)|c for the triu(192) index k; k in [18528,18592) maps to
// (j, 192) with cf[:,192]==1.0 so A[b,k] = cf[b,j] (the appended `bottom`).
__global__ void pairs_kernel(int* __restrict__ pairs) {
  int r = threadIdx.x;
  if (r < 192) {
    int off = 192 * r - (r * (r - 1)) / 2;
    for (int c = r; c < 192; ++c) pairs[off + c - r] = (r << 16) | c;
  } else if (r == 192) {
    for (int j = 0; j < 64; ++j) pairs[18528 + j] = (j << 16) | 192;
  }
}

// ---------------------------------------------------------------- pack A (f32 row-major -> bf16 tiles [mt][kt][128][32])
__global__ __launch_bounds__(256) void packA_kernel(const float* __restrict__ A,
                                                    bf16* __restrict__ Ap, int K) {
  const int t = threadIdx.x;
  const int KT = K >> 5;
  const size_t tile = ((size_t)blockIdx.x * KT + blockIdx.y) * (128 * 32);
  for (int c = t; c < 512; c += 256) {
    const int mm = c >> 2, koct = (c & 3) * 8;
    const float* src = A + (size_t)(blockIdx.x * 128 + mm) * K + blockIdx.y * 32 + koct;
    f32x4 f0 = *(const f32x4*)src;
    f32x4 f1 = *(const f32x4*)(src + 4);
    __align__(16) bf16 h[8];
    h[0]=(bf16)f0[0]; h[1]=(bf16)f0[1]; h[2]=(bf16)f0[2]; h[3]=(bf16)f0[3];
    h[4]=(bf16)f1[0]; h[5]=(bf16)f1[1]; h[6]=(bf16)f1[2]; h[7]=(bf16)f1[3];
    *(i32x4*)(Ap + tile + (size_t)c * 8) = *(const i32x4*)h;
  }
}

// ---------------------------------------------------------------- pack B (f32 [K][N] -> bf16 tiles [nt][kt][BNp][32], transposed via LDS)
template <int BNp>
__global__ __launch_bounds__(256) void packB_kernel(const float* __restrict__ B,
                                                    bf16* __restrict__ Bp, int K, int N) {
  constexpr int LS = BNp + 2;  // odd-ish word stride -> conflict-free column reads
  __shared__ float sLB[32 * LS];
  const int t = threadIdx.x;
  const int KT = K >> 5;
  for (int idx = t; idx < 32 * BNp; idx += 256) {
    const int kk = idx / BNp, nn = idx - kk * BNp;
    sLB[kk * LS + nn] = B[(size_t)(blockIdx.y * 32 + kk) * N + blockIdx.x * BNp + nn];
  }
  __syncthreads();
  const size_t tile = ((size_t)blockIdx.x * KT + blockIdx.y) * ((size_t)BNp * 32);
  for (int c = t; c < BNp * 4; c += 256) {
    const int nn = c >> 2, koct = (c & 3) * 8;
    __align__(16) bf16 h[8];
#pragma unroll
    for (int j = 0; j < 8; ++j) h[j] = (bf16)sLB[(koct + j) * LS + nn];
    *(i32x4*)(Bp + tile + (size_t)c * 8) = *(const i32x4*)h;
  }
}

// ---------------------------------------------------------------- generic MFMA GEMM, m97-style K loop
// A packed [mt BM][kt][BM][32], B packed [nt BN][kt][BN][32]. 256 threads, 2x2 waves.
// Epilogue: optional f32 row-major write (ldF) and/or packed-A write for the next GEMM
// (BMn = 1<<bmsh rows per tile, ktN = nextK/32 tiles).
template <int BM, int BN, int MF, int NF>
__global__ __launch_bounds__(256, 2) void gemm_kernel(
    const bf16* __restrict__ Ap, const bf16* __restrict__ Bp,
    const float* __restrict__ bias,
    float* __restrict__ outF, int ldF,
    bf16* __restrict__ outP, int ktN, int bmsh,
    int KT, int M0, int relu_flag) {
  __shared__ __align__(16) bf16 sA[BM * 32];
  __shared__ __align__(16) bf16 sB[BN * 32];
  const int t = threadIdx.x;
  const int bx = blockIdx.x, by = blockIdx.y;
  const int wid = t >> 6, lane = t & 63;
  const int wm = (wid >> 1) * (MF * 16);
  const int wn = (wid & 1) * (NF * 16);
  const int r16 = lane & 15, q = lane >> 4;

  f32x4 acc[MF][NF];
#pragma unroll
  for (int i = 0; i < MF; ++i)
#pragma unroll
    for (int j = 0; j < NF; ++j) acc[i][j] = f32x4{0.f, 0.f, 0.f, 0.f};

  const bf16* aBase = Ap + (size_t)bx * KT * (BM * 32);
  const bf16* bBase = Bp + (size_t)by * KT * (BN * 32);
  constexpr int A_CH = BM * 4;  // 16B chunks per A tile
  constexpr int B_CH = BN * 4;

  for (int kt = 0; kt < KT; ++kt) {
    const bf16* ag = aBase + (size_t)kt * (BM * 32);
    const bf16* bg = bBase + (size_t)kt * (BN * 32);
#pragma unroll
    for (int c = t; c < A_CH; c += 256) async16(sA + c * 8, ag + c * 8);
#pragma unroll
    for (int c = t; c < B_CH; c += 256) async16(sB + c * 8, bg + c * 8);
    __syncthreads();
    v8bf af[MF], bfr[NF];
#pragma unroll
    for (int i = 0; i < MF; ++i) af[i]  = *(const v8bf*)(sA + (wm + i * 16 + r16) * 32 + q * 8);
#pragma unroll
    for (int j = 0; j < NF; ++j) bfr[j] = *(const v8bf*)(sB + (wn + j * 16 + r16) * 32 + q * 8);
#pragma unroll
    for (int i = 0; i < MF; ++i)
#pragma unroll
      for (int j = 0; j < NF; ++j)
        acc[i][j] = __builtin_amdgcn_mfma_f32_16x16x32_bf16(af[i], bfr[j], acc[i][j], 0, 0, 0);
    __syncthreads();
  }

#pragma unroll
  for (int j = 0; j < NF; ++j) {
    const int gn = by * BN + wn + j * 16 + r16;
    const float bv = bias[gn];
#pragma unroll
    for (int i = 0; i < MF; ++i) {
      const int gm0 = M0 + bx * BM + wm + i * 16 + q * 4;
#pragma unroll
      for (int r = 0; r < 4; ++r) {
        float v = acc[i][j][r] + bv;
        if (relu_flag) v = fmaxf(v, 0.f);
        const int gm = gm0 + r;
        if (outF) outF[(size_t)gm * ldF + gn] = v;
        if (outP) {
          const int mt = gm >> bmsh, mm = gm & ((1 << bmsh) - 1);
          outP[(((size_t)mt * ktN + (gn >> 5)) << (bmsh + 5)) + ((size_t)mm << 5) + (gn & 31)] = (bf16)v;
        }
      }
    }
  }
}

// ---------------------------------------------------------------- embedding gather-sum -> cf[:,128:192]
__global__ __launch_bounds__(256) void embed_kernel(const int* __restrict__ xs,
                                                    const float* __restrict__ emb,
                                                    float* __restrict__ cf) {
  const int wid = threadIdx.x >> 6, lane = threadIdx.x & 63;
  const int b = blockIdx.x * 4 + wid;
  const int* row = xs + (size_t)b * 50;
  float acc = 0.f;
  for (int h = 0; h < 50; ++h) {
    int idx = row[h];
    acc += emb[(size_t)idx * 64 + lane];
  }
  cf[(size_t)b * 193 + 128 + lane] = acc;
}

// ---------------------------------------------------------------- batchnorm stats over z [4096][64]
__global__ __launch_bounds__(256) void bnstats_kernel(const float* __restrict__ z,
                                                      float* __restrict__ stats) {
  const int j = blockIdx.x, t = threadIdx.x;
  float s = 0.f, s2 = 0.f;
  for (int b = t; b < 4096; b += 256) {
    float v = z[(size_t)b * 64 + j];
    s += v; s2 += v * v;
  }
  __shared__ float sh[256], sh2[256];
  sh[t] = s; sh2[t] = s2;
  __syncthreads();
  for (int o = 128; o > 0; o >>= 1) {
    if (t < o) { sh[t] += sh[t + o]; sh2[t] += sh2[t + o]; }
    __syncthreads();
  }
  if (t == 0) {
    float mu = sh[0] * (1.f / 4096.f);
    float var = sh2[0] * (1.f / 4096.f) - mu * mu;
    stats[j] = mu;
    stats[64 + j] = rsqrtf(var + 1e-5f);
  }
}

// ---------------------------------------------------------------- normalize -> cf[:,64:128], d_out tail, cf[:,192]=1
__global__ __launch_bounds__(256) void cfbuild_kernel(const float* __restrict__ z,
                                                      const float* __restrict__ stats,
                                                      const float* __restrict__ gamma,
                                                      const float* __restrict__ beta,
                                                      float* __restrict__ cf,
                                                      float* __restrict__ dout) {
  const int wid = threadIdx.x >> 6, lane = threadIdx.x & 63;
  const int b = blockIdx.x * 4 + wid;
  const float mu = stats[lane], rstd = stats[64 + lane];
  const float xe = gamma[lane] * (z[(size_t)b * 64 + lane] - mu) * rstd + beta[lane];
  cf[(size_t)b * 193 + 64 + lane] = xe;
  dout[4096 + (size_t)b * 64 + lane] = xe;
  if (lane == 0) cf[(size_t)b * 193 + 192] = 1.f;
}

// ---------------------------------------------------------------- interaction A generation -> packed bf16 tiles
__global__ __launch_bounds__(256, 2) void agen_kernel(const float* __restrict__ cf,
                                                      const int* __restrict__ pairs,
                                                      bf16* __restrict__ Ap, int rowBase) {
  __shared__ float sCF[64 * 193];
  const int t = threadIdx.x;
  const int gRow0 = rowBase + blockIdx.x * 64;
  for (int i = t; i < 64 * 193; i += 256) sCF[i] = cf[(size_t)gRow0 * 193 + i];
  __syncthreads();
  const int kt0 = blockIdx.y * 73;
  const int kt1 = (kt0 + 73 < 581) ? (kt0 + 73) : 581;
  const int mm = t >> 2, qrt = t & 3;
  const int lmt = blockIdx.x >> 1;
  const int mmt = (blockIdx.x & 1) * 64 + mm;
  const float* myrow = sCF + mm * 193;
  for (int kt = kt0; kt < kt1; ++kt) {
    const int kb = kt * 32 + qrt * 8;
    __align__(16) bf16 h[8];
#pragma unroll
    for (int j = 0; j < 8; ++j) {
      const int pr = pairs[kb + j];
      h[j] = (bf16)(myrow[pr >> 16] * myrow[pr & 0xffff]);
    }
    *(i32x4*)(Ap + (((size_t)lmt * 581 + kt) * 128 + mmt) * 32 + qrt * 8) = *(const i32x4*)h;
  }
}

// ---------------------------------------------------------------- final dot (512->1) + sigmoid
__global__ __launch_bounds__(256) void topdot_kernel(const float* __restrict__ t2,
                                                     const float* __restrict__ w,
                                                     const float* __restrict__ b3,
                                                     float* __restrict__ dout) {
  const int wid = threadIdx.x >> 6, lane = threadIdx.x & 63;
  const int b = blockIdx.x * 4 + wid;
  const f32x4* row = (const f32x4*)(t2 + (size_t)b * 512);
  const f32x4* wv = (const f32x4*)w;
  float s = 0.f;
#pragma unroll
  for (int i = 0; i < 2; ++i) {
    f32x4 a = row[lane * 2 + i], c = wv[lane * 2 + i];
    s += a[0] * c[0] + a[1] * c[1] + a[2] * c[2] + a[3] * c[3];
  }
  for (int m = 32; m > 0; m >>= 1) s += __shfl_xor(s, m, 64);
  if (lane == 0) dout[b] = 1.f / (1.f + __expf(-(s + b3[0])));
}

// ================================================================ launch
extern "C" void kernel_launch(void* const* d_in, const int* in_sizes, int n_in,
                              void* d_out, int out_size, void* d_ws, size_t ws_size,
                              hipStream_t stream) {
  const int*   xs   = (const int*)  d_in[0];
  const float* xd   = (const float*)d_in[1];
  const float* xep  = (const float*)d_in[2];
  const float* emb  = (const float*)d_in[3];
  const float* pw1  = (const float*)d_in[4];
  const float* pb1  = (const float*)d_in[5];
  const float* pw2  = (const float*)d_in[6];
  const float* pb2  = (const float*)d_in[7];
  const float* gmma = (const float*)d_in[8];
  const float* beta = (const float*)d_in[9];
  const float* bw1  = (const float*)d_in[10];
  const float* bb1  = (const float*)d_in[11];
  const float* bw2  = (const float*)d_in[12];
  const float* bb2  = (const float*)d_in[13];
  const float* tw1  = (const float*)d_in[14];
  const float* tb1  = (const float*)d_in[15];
  const float* tw2  = (const float*)d_in[16];
  const float* tb2  = (const float*)d_in[17];
  const float* tw3  = (const float*)d_in[18];
  const float* tb3  = (const float*)d_in[19];
  float* out = (float*)d_out;

  uint8_t* base = (uint8_t*)d_ws;
  size_t off = 0;
  auto alloc = [&](size_t b) {
    void* p = base + off;
    off = (off + b + 511) & ~((size_t)511);
    return p;
  };
  int*  pairs = (int*) alloc((size_t)18592 * 4);
  bf16* Xp    = (bf16*)alloc((size_t)4096 * 768 * 2);
  bf16* Xd    = (bf16*)alloc((size_t)4096 * 256 * 2);
  bf16* Bpw1  = (bf16*)alloc((size_t)768 * 256 * 2);
  bf16* Bpw2  = (bf16*)alloc((size_t)256 * 64 * 2);
  bf16* Bbw1  = (bf16*)alloc((size_t)256 * 512 * 2);
  bf16* Bbw2  = (bf16*)alloc((size_t)512 * 64 * 2);
  bf16* Btw1  = (bf16*)alloc((size_t)18592 * 1024 * 2);
  bf16* Btw2  = (bf16*)alloc((size_t)1024 * 512 * 2);
  bf16* hbuf  = (bf16*)alloc((size_t)4096 * 256 * 2);
  float* z    = (float*)alloc((size_t)4096 * 64 * 4);
  float* stats= (float*)alloc((size_t)128 * 4);
  bf16* b0    = (bf16*)alloc((size_t)4096 * 512 * 2);
  float* cf   = (float*)alloc((size_t)4096 * 193 * 4);
  bf16* t1    = (bf16*)alloc((size_t)4096 * 1024 * 2);
  float* t2   = (float*)alloc((size_t)4096 * 512 * 4);
  size_t fixedEnd = off;
  int chunk = 4096;
  while (chunk > 512 && fixedEnd + (size_t)chunk * 18592 * 2 > ws_size) chunk >>= 1;
  bf16* ApBig = (bf16*)alloc((size_t)chunk * 18592 * 2);

  pairs_kernel<<<1, 256, 0, stream>>>(pairs);

  packA_kernel<<<dim3(32, 24), 256, 0, stream>>>(xep, Xp, 768);
  packA_kernel<<<dim3(32, 8), 256, 0, stream>>>(xd, Xd, 256);
  packB_kernel<128><<<dim3(2, 24), 256, 0, stream>>>(pw1, Bpw1, 768, 256);
  packB_kernel<64><<<dim3(1, 8), 256, 0, stream>>>(pw2, Bpw2, 256, 64);
  packB_kernel<128><<<dim3(4, 8), 256, 0, stream>>>(bw1, Bbw1, 256, 512);
  packB_kernel<64><<<dim3(1, 16), 256, 0, stream>>>(bw2, Bbw2, 512, 64);
  packB_kernel<128><<<dim3(8, 581), 256, 0, stream>>>(tw1, Btw1, 18592, 1024);
  packB_kernel<128><<<dim3(4, 32), 256, 0, stream>>>(tw2, Btw2, 1024, 512);

  embed_kernel<<<1024, 256, 0, stream>>>(xs, emb, cf);

  // proj MLP: h = relu(xep@pw1+pb1) [packed BM=64]; z = h@pw2+pb2 (f32)
  gemm_kernel<128, 128, 4, 4><<<dim3(32, 2), 256, 0, stream>>>(
      Xp, Bpw1, pb1, nullptr, 0, hbuf, 8, 6, 24, 0, 1);
  gemm_kernel<64, 64, 2, 2><<<dim3(64, 1), 256, 0, stream>>>(
      hbuf, Bpw2, pb2, z, 64, nullptr, 0, 0, 8, 0, 0);
  // bottom MLP: b0 = relu(xd@bw1+bb1) [packed BM=64]; bottom = relu(b0@bw2+bb2) -> cf[:,0:64]
  gemm_kernel<128, 128, 4, 4><<<dim3(32, 4), 256, 0, stream>>>(
      Xd, Bbw1, bb1, nullptr, 0, b0, 16, 6, 8, 0, 1);
  gemm_kernel<64, 64, 2, 2><<<dim3(64, 1), 256, 0, stream>>>(
      b0, Bbw2, bb2, cf, 193, nullptr, 0, 0, 16, 0, 1);

  bnstats_kernel<<<64, 256, 0, stream>>>(z, stats);
  cfbuild_kernel<<<1024, 256, 0, stream>>>(z, stats, gmma, beta, cf, out);

  // interaction + big GEMM, row-chunked to fit ws
  for (int c0 = 0; c0 < 4096; c0 += chunk) {
    agen_kernel<<<dim3(chunk / 64, 8), 256, 0, stream>>>(cf, pairs, ApBig, c0);
    gemm_kernel<128, 128, 4, 4><<<dim3(chunk / 128, 8), 256, 0, stream>>>(
        ApBig, Btw1, tb1, nullptr, 0, t1, 32, 7, 581, c0, 1);
  }

  // top2: t2 = relu(t1@tw2+tb2) (f32 row-major)
  gemm_kernel<128, 128, 4, 4><<<dim3(32, 4), 256, 0, stream>>>(
      t1, Btw2, tb2, t2, 512, nullptr, 0, 0, 32, 0, 1);
  // top3: sigmoid(t2@tw3+tb3) -> out[0:4096]
  topdot_kernel<<<1024, 256, 0, stream>>>(t2, tw3, tb3, out);
}

// Round 2
// 532.888 us; speedup vs baseline: 1.4725x; 1.4725x over previous
//
#include <hip/hip_runtime.h>
#include <hip/hip_bf16.h>
#include <cstdint>
#include <cstddef>

typedef __bf16 bf16;
typedef __bf16 v8bf  __attribute__((ext_vector_type(8)));
typedef float  f32x4 __attribute__((ext_vector_type(4)));
typedef int    i32x4 __attribute__((ext_vector_type(4)));
typedef int    i32x2 __attribute__((ext_vector_type(2)));

// ---------------------------------------------------------------- async copy
__device__ __forceinline__ void async16(bf16* lds, const bf16* g) {
  __builtin_amdgcn_global_load_lds(
      (const __attribute__((address_space(1))) unsigned int*)g,
      (__attribute__((address_space(3))) unsigned int*)lds, 16, 0, 0);
}

// LDS tile layout is XOR-swizzled: 16B chunk (row, qs) holds global quarter
// q = (qs - (row>>1)) & 3. Reader of global (row, q) uses qs = (q + (row>>1)) & 3.
// This makes ds_read_b128 fragment reads 2-way (free) instead of 8-way.

// ---------------------------------------------------------------- pairs table
__global__ void pairs_kernel(int* __restrict__ pairs) {
  int r = threadIdx.x;
  if (r < 192) {
    int off = 192 * r - (r * (r - 1)) / 2;
    for (int c = r; c < 192; ++c) pairs[off + c - r] = (r << 16) | c;
  } else if (r == 192) {
    for (int j = 0; j < 64; ++j) pairs[18528 + j] = (j << 16) | 192;
  }
}

// ---------------------------------------------------------------- pack A (f32 row-major -> bf16 tiles [mt][kt][BMp][32])
template <int BMp>
__global__ __launch_bounds__(256) void packA_kernel(const float* __restrict__ A,
                                                    bf16* __restrict__ Ap, int K) {
  const int t = threadIdx.x;
  const int KT = K >> 5;
  const size_t tile = ((size_t)blockIdx.x * KT + blockIdx.y) * (BMp * 32);
  for (int c = t; c < BMp * 4; c += 256) {
    const int mm = c >> 2, koct = (c & 3) * 8;
    const float* src = A + (size_t)(blockIdx.x * BMp + mm) * K + blockIdx.y * 32 + koct;
    f32x4 f0 = *(const f32x4*)src;
    f32x4 f1 = *(const f32x4*)(src + 4);
    __align__(16) bf16 h[8];
    h[0]=(bf16)f0[0]; h[1]=(bf16)f0[1]; h[2]=(bf16)f0[2]; h[3]=(bf16)f0[3];
    h[4]=(bf16)f1[0]; h[5]=(bf16)f1[1]; h[6]=(bf16)f1[2]; h[7]=(bf16)f1[3];
    *(i32x4*)(Ap + tile + (size_t)c * 8) = *(const i32x4*)h;
  }
}

// ---------------------------------------------------------------- pack B (f32 [K][N] -> bf16 tiles [nt][kt][BNp][32])
template <int BNp>
__global__ __launch_bounds__(256) void packB_kernel(const float* __restrict__ B,
                                                    bf16* __restrict__ Bp, int K, int N) {
  constexpr int LS = BNp + 2;
  __shared__ float sLB[32 * LS];
  const int t = threadIdx.x;
  const int KT = K >> 5;
  for (int idx = t; idx < 32 * BNp; idx += 256) {
    const int kk = idx / BNp, nn = idx - kk * BNp;
    sLB[kk * LS + nn] = B[(size_t)(blockIdx.y * 32 + kk) * N + blockIdx.x * BNp + nn];
  }
  __syncthreads();
  const size_t tile = ((size_t)blockIdx.x * KT + blockIdx.y) * ((size_t)BNp * 32);
  for (int c = t; c < BNp * 4; c += 256) {
    const int nn = c >> 2, koct = (c & 3) * 8;
    __align__(16) bf16 h[8];
#pragma unroll
    for (int j = 0; j < 8; ++j) h[j] = (bf16)sLB[(koct + j) * LS + nn];
    *(i32x4*)(Bp + tile + (size_t)c * 8) = *(const i32x4*)h;
  }
}

// ---------------------------------------------------------------- generic MFMA GEMM (swizzled LDS)
template <int BM, int BN, int MF, int NF>
__global__ __launch_bounds__(256, 2) void gemm_kernel(
    const bf16* __restrict__ Ap, const bf16* __restrict__ Bp,
    const float* __restrict__ bias,
    float* __restrict__ outF, int ldF,
    bf16* __restrict__ outP, int ktN, int bmsh,
    int KT, int M0, int relu_flag) {
  __shared__ __align__(16) bf16 sA[BM * 32];
  __shared__ __align__(16) bf16 sB[BN * 32];
  const int t = threadIdx.x;
  const int bx = blockIdx.x, by = blockIdx.y;
  const int wid = t >> 6, lane = t & 63;
  const int wm = (wid >> 1) * (MF * 16);
  const int wn = (wid & 1) * (NF * 16);
  const int r16 = lane & 15, q = lane >> 4;

  f32x4 acc[MF][NF];
#pragma unroll
  for (int i = 0; i < MF; ++i)
#pragma unroll
    for (int j = 0; j < NF; ++j) acc[i][j] = f32x4{0.f, 0.f, 0.f, 0.f};

  const bf16* aBase = Ap + (size_t)bx * KT * (BM * 32);
  const bf16* bBase = Bp + (size_t)by * KT * (BN * 32);
  constexpr int A_CH = BM * 4;
  constexpr int B_CH = BN * 4;

  for (int kt = 0; kt < KT; ++kt) {
    const bf16* ag = aBase + (size_t)kt * (BM * 32);
    const bf16* bg = bBase + (size_t)kt * (BN * 32);
#pragma unroll
    for (int c = t; c < A_CH; c += 256) {
      const int row = c >> 2, qs = c & 3, qg = (qs - (row >> 1)) & 3;
      async16(sA + c * 8, ag + row * 32 + qg * 8);
    }
#pragma unroll
    for (int c = t; c < B_CH; c += 256) {
      const int row = c >> 2, qs = c & 3, qg = (qs - (row >> 1)) & 3;
      async16(sB + c * 8, bg + row * 32 + qg * 8);
    }
    __syncthreads();
    v8bf af[MF], bfr[NF];
#pragma unroll
    for (int i = 0; i < MF; ++i) {
      const int row = wm + i * 16 + r16;
      af[i] = *(const v8bf*)(sA + row * 32 + (((q + (row >> 1)) & 3) * 8));
    }
#pragma unroll
    for (int j = 0; j < NF; ++j) {
      const int row = wn + j * 16 + r16;
      bfr[j] = *(const v8bf*)(sB + row * 32 + (((q + (row >> 1)) & 3) * 8));
    }
#pragma unroll
    for (int i = 0; i < MF; ++i)
#pragma unroll
      for (int j = 0; j < NF; ++j)
        acc[i][j] = __builtin_amdgcn_mfma_f32_16x16x32_bf16(af[i], bfr[j], acc[i][j], 0, 0, 0);
    __syncthreads();
  }

#pragma unroll
  for (int j = 0; j < NF; ++j) {
    const int gn = by * BN + wn + j * 16 + r16;
    const float bv = bias[gn];
#pragma unroll
    for (int i = 0; i < MF; ++i) {
      const int gm0 = M0 + bx * BM + wm + i * 16 + q * 4;
#pragma unroll
      for (int r = 0; r < 4; ++r) {
        float v = acc[i][j][r] + bv;
        if (relu_flag) v = fmaxf(v, 0.f);
        const int gm = gm0 + r;
        if (outF) outF[(size_t)gm * ldF + gn] = v;
        if (outP) {
          const int mt = gm >> bmsh, mm = gm & ((1 << bmsh) - 1);
          outP[(((size_t)mt * ktN + (gn >> 5)) << (bmsh + 5)) + ((size_t)mm << 5) + (gn & 31)] = (bf16)v;
        }
      }
    }
  }
}

// ---------------------------------------------------------------- split-K MFMA GEMM -> f32 partials [S][Mchunk][N]
template <int BM, int BN, int MF, int NF>
__global__ __launch_bounds__(256, 2) void gemm_splitk_kernel(
    const bf16* __restrict__ Ap, const bf16* __restrict__ Bp,
    float* __restrict__ part, int KT, int S, int Mchunk, int N) {
  __shared__ __align__(16) bf16 sA[BM * 32];
  __shared__ __align__(16) bf16 sB[BN * 32];
  const int t = threadIdx.x;
  const int bx = blockIdx.x, by = blockIdx.y, bz = blockIdx.z;
  const int wid = t >> 6, lane = t & 63;
  const int wm = (wid >> 1) * (MF * 16);
  const int wn = (wid & 1) * (NF * 16);
  const int r16 = lane & 15, q = lane >> 4;
  const int kt0 = (KT * bz) / S, kt1 = (KT * (bz + 1)) / S;

  f32x4 acc[MF][NF];
#pragma unroll
  for (int i = 0; i < MF; ++i)
#pragma unroll
    for (int j = 0; j < NF; ++j) acc[i][j] = f32x4{0.f, 0.f, 0.f, 0.f};

  const bf16* aBase = Ap + (size_t)bx * KT * (BM * 32);
  const bf16* bBase = Bp + (size_t)by * KT * (BN * 32);
  constexpr int A_CH = BM * 4;
  constexpr int B_CH = BN * 4;

  for (int kt = kt0; kt < kt1; ++kt) {
    const bf16* ag = aBase + (size_t)kt * (BM * 32);
    const bf16* bg = bBase + (size_t)kt * (BN * 32);
#pragma unroll
    for (int c = t; c < A_CH; c += 256) {
      const int row = c >> 2, qs = c & 3, qg = (qs - (row >> 1)) & 3;
      async16(sA + c * 8, ag + row * 32 + qg * 8);
    }
#pragma unroll
    for (int c = t; c < B_CH; c += 256) {
      const int row = c >> 2, qs = c & 3, qg = (qs - (row >> 1)) & 3;
      async16(sB + c * 8, bg + row * 32 + qg * 8);
    }
    __syncthreads();
    v8bf af[MF], bfr[NF];
#pragma unroll
    for (int i = 0; i < MF; ++i) {
      const int row = wm + i * 16 + r16;
      af[i] = *(const v8bf*)(sA + row * 32 + (((q + (row >> 1)) & 3) * 8));
    }
#pragma unroll
    for (int j = 0; j < NF; ++j) {
      const int row = wn + j * 16 + r16;
      bfr[j] = *(const v8bf*)(sB + row * 32 + (((q + (row >> 1)) & 3) * 8));
    }
#pragma unroll
    for (int i = 0; i < MF; ++i)
#pragma unroll
      for (int j = 0; j < NF; ++j)
        acc[i][j] = __builtin_amdgcn_mfma_f32_16x16x32_bf16(af[i], bfr[j], acc[i][j], 0, 0, 0);
    __syncthreads();
  }

  float* pBase = part + (size_t)bz * Mchunk * N;
#pragma unroll
  for (int j = 0; j < NF; ++j) {
    const int gn = by * BN + wn + j * 16 + r16;
#pragma unroll
    for (int i = 0; i < MF; ++i) {
      const int gm0 = bx * BM + wm + i * 16 + q * 4;
#pragma unroll
      for (int r = 0; r < 4; ++r)
        pBase[(size_t)(gm0 + r) * N + gn] = acc[i][j][r];
    }
  }
}

// ---------------------------------------------------------------- split-K reduce: sum S partials, +bias, relu, pack bf16 t1 (BM=64 layout)
__global__ __launch_bounds__(256) void reducek_kernel(const float* __restrict__ part,
                                                      const float* __restrict__ bias,
                                                      bf16* __restrict__ t1,
                                                      int S, int Mchunk, int M0) {
  const int idx = blockIdx.x * 256 + threadIdx.x;      // one f32x4 per thread
  const int gm = idx >> 8;                              // [0, Mchunk)
  const int gn4 = (idx & 255) * 4;                      // N = 1024
  f32x4 v = f32x4{0.f, 0.f, 0.f, 0.f};
  for (int s = 0; s < S; ++s)
    v += *(const f32x4*)(part + ((size_t)s * Mchunk + gm) * 1024 + gn4);
  const f32x4 bv = *(const f32x4*)(bias + gn4);
  __align__(8) bf16 h[4];
#pragma unroll
  for (int r = 0; r < 4; ++r) h[r] = (bf16)fmaxf(v[r] + bv[r], 0.f);
  const int G = M0 + gm;
  const int mt = G >> 6, mm = G & 63, kt = gn4 >> 5;
  *(i32x2*)(t1 + (((size_t)mt * 32 + kt) << 11) + (mm << 5) + (gn4 & 31)) = *(const i32x2*)h;
}

// ---------------------------------------------------------------- embedding gather-sum -> cf[:,128:192]
__global__ __launch_bounds__(256) void embed_kernel(const int* __restrict__ xs,
                                                    const float* __restrict__ emb,
                                                    float* __restrict__ cf) {
  const int wid = threadIdx.x >> 6, lane = threadIdx.x & 63;
  const int b = blockIdx.x * 4 + wid;
  const int* row = xs + (size_t)b * 50;
  float acc = 0.f;
  for (int h = 0; h < 50; ++h) {
    int idx = row[h];
    acc += emb[(size_t)idx * 64 + lane];
  }
  cf[(size_t)b * 193 + 128 + lane] = acc;
}

// ---------------------------------------------------------------- batchnorm stats over z [4096][64]
__global__ __launch_bounds__(256) void bnstats_kernel(const float* __restrict__ z,
                                                      float* __restrict__ stats) {
  const int j = blockIdx.x, t = threadIdx.x;
  float s = 0.f, s2 = 0.f;
  for (int b = t; b < 4096; b += 256) {
    float v = z[(size_t)b * 64 + j];
    s += v; s2 += v * v;
  }
  __shared__ float sh[256], sh2[256];
  sh[t] = s; sh2[t] = s2;
  __syncthreads();
  for (int o = 128; o > 0; o >>= 1) {
    if (t < o) { sh[t] += sh[t + o]; sh2[t] += sh2[t + o]; }
    __syncthreads();
  }
  if (t == 0) {
    float mu = sh[0] * (1.f / 4096.f);
    float var = sh2[0] * (1.f / 4096.f) - mu * mu;
    stats[j] = mu;
    stats[64 + j] = rsqrtf(var + 1e-5f);
  }
}

// ---------------------------------------------------------------- normalize -> cf[:,64:128], d_out tail, cf[:,192]=1
__global__ __launch_bounds__(256) void cfbuild_kernel(const float* __restrict__ z,
                                                      const float* __restrict__ stats,
                                                      const float* __restrict__ gamma,
                                                      const float* __restrict__ beta,
                                                      float* __restrict__ cf,
                                                      float* __restrict__ dout) {
  const int wid = threadIdx.x >> 6, lane = threadIdx.x & 63;
  const int b = blockIdx.x * 4 + wid;
  const float mu = stats[lane], rstd = stats[64 + lane];
  const float xe = gamma[lane] * (z[(size_t)b * 64 + lane] - mu) * rstd + beta[lane];
  cf[(size_t)b * 193 + 64 + lane] = xe;
  dout[4096 + (size_t)b * 64 + lane] = xe;
  if (lane == 0) cf[(size_t)b * 193 + 192] = 1.f;
}

// ---------------------------------------------------------------- interaction A generation -> packed bf16 tiles (BM=128)
__global__ __launch_bounds__(256, 2) void agen_kernel(const float* __restrict__ cf,
                                                      const int* __restrict__ pairs,
                                                      bf16* __restrict__ Ap, int rowBase) {
  __shared__ float sCF[64 * 193];
  const int t = threadIdx.x;
  const int gRow0 = rowBase + blockIdx.x * 64;
  for (int i = t; i < 64 * 193; i += 256) sCF[i] = cf[(size_t)gRow0 * 193 + i];
  __syncthreads();
  const int kt0 = blockIdx.y * 73;
  const int kt1 = (kt0 + 73 < 581) ? (kt0 + 73) : 581;
  const int mm = t >> 2, qrt = t & 3;
  const int lmt = blockIdx.x >> 1;
  const int mmt = (blockIdx.x & 1) * 64 + mm;
  const float* myrow = sCF + mm * 193;
  for (int kt = kt0; kt < kt1; ++kt) {
    const int kb = kt * 32 + qrt * 8;
    __align__(16) bf16 h[8];
#pragma unroll
    for (int j = 0; j < 8; ++j) {
      const int pr = pairs[kb + j];
      h[j] = (bf16)(myrow[pr >> 16] * myrow[pr & 0xffff]);
    }
    *(i32x4*)(Ap + (((size_t)lmt * 581 + kt) * 128 + mmt) * 32 + qrt * 8) = *(const i32x4*)h;
  }
}

// ---------------------------------------------------------------- final dot (512->1) + sigmoid
__global__ __launch_bounds__(256) void topdot_kernel(const float* __restrict__ t2,
                                                     const float* __restrict__ w,
                                                     const float* __restrict__ b3,
                                                     float* __restrict__ dout) {
  const int wid = threadIdx.x >> 6, lane = threadIdx.x & 63;
  const int b = blockIdx.x * 4 + wid;
  const f32x4* row = (const f32x4*)(t2 + (size_t)b * 512);
  const f32x4* wv = (const f32x4*)w;
  float s = 0.f;
#pragma unroll
  for (int i = 0; i < 2; ++i) {
    f32x4 a = row[lane * 2 + i], c = wv[lane * 2 + i];
    s += a[0] * c[0] + a[1] * c[1] + a[2] * c[2] + a[3] * c[3];
  }
  for (int m = 32; m > 0; m >>= 1) s += __shfl_xor(s, m, 64);
  if (lane == 0) dout[b] = 1.f / (1.f + __expf(-(s + b3[0])));
}

// ================================================================ launch
extern "C" void kernel_launch(void* const* d_in, const int* in_sizes, int n_in,
                              void* d_out, int out_size, void* d_ws, size_t ws_size,
                              hipStream_t stream) {
  const int*   xs   = (const int*)  d_in[0];
  const float* xd   = (const float*)d_in[1];
  const float* xep  = (const float*)d_in[2];
  const float* emb  = (const float*)d_in[3];
  const float* pw1  = (const float*)d_in[4];
  const float* pb1  = (const float*)d_in[5];
  const float* pw2  = (const float*)d_in[6];
  const float* pb2  = (const float*)d_in[7];
  const float* gmma = (const float*)d_in[8];
  const float* beta = (const float*)d_in[9];
  const float* bw1  = (const float*)d_in[10];
  const float* bb1  = (const float*)d_in[11];
  const float* bw2  = (const float*)d_in[12];
  const float* bb2  = (const float*)d_in[13];
  const float* tw1  = (const float*)d_in[14];
  const float* tb1  = (const float*)d_in[15];
  const float* tw2  = (const float*)d_in[16];
  const float* tb2  = (const float*)d_in[17];
  const float* tw3  = (const float*)d_in[18];
  const float* tb3  = (const float*)d_in[19];
  float* out = (float*)d_out;

  uint8_t* base = (uint8_t*)d_ws;
  size_t off = 0;
  auto alloc = [&](size_t b) {
    void* p = base + off;
    off = (off + b + 511) & ~((size_t)511);
    return p;
  };
  int*  pairs = (int*) alloc((size_t)18592 * 4);
  bf16* Xp    = (bf16*)alloc((size_t)4096 * 768 * 2);
  bf16* Xd    = (bf16*)alloc((size_t)4096 * 256 * 2);
  bf16* Bpw1  = (bf16*)alloc((size_t)768 * 256 * 2);
  bf16* Bpw2  = (bf16*)alloc((size_t)256 * 64 * 2);
  bf16* Bbw1  = (bf16*)alloc((size_t)256 * 512 * 2);
  bf16* Bbw2  = (bf16*)alloc((size_t)512 * 64 * 2);
  bf16* Btw1  = (bf16*)alloc((size_t)18592 * 1024 * 2);
  bf16* Btw2  = (bf16*)alloc((size_t)1024 * 512 * 2);
  bf16* hbuf  = (bf16*)alloc((size_t)4096 * 256 * 2);
  float* z    = (float*)alloc((size_t)4096 * 64 * 4);
  float* stats= (float*)alloc((size_t)128 * 4);
  bf16* b0    = (bf16*)alloc((size_t)4096 * 512 * 2);
  float* cf   = (float*)alloc((size_t)4096 * 193 * 4);
  bf16* t1    = (bf16*)alloc((size_t)4096 * 1024 * 2);
  float* t2   = (float*)alloc((size_t)4096 * 512 * 4);
  size_t fixedEnd = off;

  // pick (chunk, S) so Ap + partials fit in ws
  int chunk = 512, S = 8;
  {
    const int candC[4] = {4096, 2048, 1024, 512};
    const int candS[4] = {4, 8, 8, 8};
    for (int i = 0; i < 4; ++i) {
      size_t need = fixedEnd + (size_t)candC[i] * 18592 * 2 + 1024 +
                    (size_t)candS[i] * candC[i] * 1024 * 4 + 1024;
      if (need <= ws_size) { chunk = candC[i]; S = candS[i]; break; }
    }
  }
  bf16*  ApBig = (bf16*) alloc((size_t)chunk * 18592 * 2);
  float* partK = (float*)alloc((size_t)S * chunk * 1024 * 4);

  pairs_kernel<<<1, 256, 0, stream>>>(pairs);

  packA_kernel<64><<<dim3(64, 24), 256, 0, stream>>>(xep, Xp, 768);
  packA_kernel<64><<<dim3(64, 8), 256, 0, stream>>>(xd, Xd, 256);
  packB_kernel<64><<<dim3(4, 24), 256, 0, stream>>>(pw1, Bpw1, 768, 256);
  packB_kernel<64><<<dim3(1, 8), 256, 0, stream>>>(pw2, Bpw2, 256, 64);
  packB_kernel<64><<<dim3(8, 8), 256, 0, stream>>>(bw1, Bbw1, 256, 512);
  packB_kernel<64><<<dim3(1, 16), 256, 0, stream>>>(bw2, Bbw2, 512, 64);
  packB_kernel<128><<<dim3(8, 581), 256, 0, stream>>>(tw1, Btw1, 18592, 1024);
  packB_kernel<64><<<dim3(8, 32), 256, 0, stream>>>(tw2, Btw2, 1024, 512);

  embed_kernel<<<1024, 256, 0, stream>>>(xs, emb, cf);

  // proj MLP: h = relu(xep@pw1+pb1) [packed BM=64]; z = h@pw2+pb2 (f32)
  gemm_kernel<64, 64, 2, 2><<<dim3(64, 4), 256, 0, stream>>>(
      Xp, Bpw1, pb1, nullptr, 0, hbuf, 8, 6, 24, 0, 1);
  gemm_kernel<64, 64, 2, 2><<<dim3(64, 1), 256, 0, stream>>>(
      hbuf, Bpw2, pb2, z, 64, nullptr, 0, 0, 8, 0, 0);
  // bottom MLP: b0 = relu(xd@bw1+bb1) [packed BM=64]; bottom = relu(b0@bw2+bb2) -> cf[:,0:64]
  gemm_kernel<64, 64, 2, 2><<<dim3(64, 8), 256, 0, stream>>>(
      Xd, Bbw1, bb1, nullptr, 0, b0, 16, 6, 8, 0, 1);
  gemm_kernel<64, 64, 2, 2><<<dim3(64, 1), 256, 0, stream>>>(
      b0, Bbw2, bb2, cf, 193, nullptr, 0, 0, 16, 0, 1);

  bnstats_kernel<<<64, 256, 0, stream>>>(z, stats);
  cfbuild_kernel<<<1024, 256, 0, stream>>>(z, stats, gmma, beta, cf, out);

  // interaction + big GEMM (split-K) + reduce, row-chunked to fit ws
  for (int c0 = 0; c0 < 4096; c0 += chunk) {
    agen_kernel<<<dim3(chunk / 64, 8), 256, 0, stream>>>(cf, pairs, ApBig, c0);
    gemm_splitk_kernel<128, 128, 4, 4><<<dim3(chunk / 128, 8, S), 256, 0, stream>>>(
        ApBig, Btw1, partK, 581, S, chunk, 1024);
    reducek_kernel<<<chunk, 256, 0, stream>>>(partK, tb1, t1, S, chunk, c0);
  }

  // top2: t2 = relu(t1@tw2+tb2) (f32 row-major), t1 packed BM=64
  gemm_kernel<64, 64, 2, 2><<<dim3(64, 8), 256, 0, stream>>>(
      t1, Btw2, tb2, t2, 512, nullptr, 0, 0, 32, 0, 1);
  // top3: sigmoid(t2@tw3+tb3) -> out[0:4096]
  topdot_kernel<<<1024, 256, 0, stream>>>(t2, tw3, tb3, out);
}

// Round 3
// 464.790 us; speedup vs baseline: 1.6882x; 1.1465x over previous
//
#include <hip/hip_runtime.h>
#include <hip/hip_bf16.h>
#include <cstdint>
#include <cstddef>

typedef __bf16 bf16;
typedef __bf16 v8bf  __attribute__((ext_vector_type(8)));
typedef float  f32x4 __attribute__((ext_vector_type(4)));
typedef int    i32x4 __attribute__((ext_vector_type(4)));
typedef int    i32x2 __attribute__((ext_vector_type(2)));

// ---------------------------------------------------------------- async copy
__device__ __forceinline__ void async16(bf16* lds, const bf16* g) {
  __builtin_amdgcn_global_load_lds(
      (const __attribute__((address_space(1))) unsigned int*)g,
      (__attribute__((address_space(3))) unsigned int*)lds, 16, 0, 0);
}

// LDS tile layout is XOR-swizzled: 16B chunk (row, qs) holds global quarter
// q = (qs - (row>>1)) & 3. Reader of global (row, q) uses qs = (q + (row>>1)) & 3.
// Keeps ds_read_b128 fragment reads 2-way (free) instead of 8-way. [R2: verified,
// SQ_LDS_BANK_CONFLICT 1.9e7 -> 0]

// ================================================================ prologue device funcs
__device__ __forceinline__ void pairs_dev(int* __restrict__ pairs) {
  int r = threadIdx.x;
  if (r < 192) {
    int off = 192 * r - (r * (r - 1)) / 2;
    for (int c = r; c < 192; ++c) pairs[off + c - r] = (r << 16) | c;
  } else if (r == 192) {
    for (int j = 0; j < 64; ++j) pairs[18528 + j] = (j << 16) | 192;
  }
}

// pack A (f32 row-major -> bf16 tiles [mt][kt][64][32])
__device__ __forceinline__ void packA_dev(const float* __restrict__ A,
                                          bf16* __restrict__ Ap, int K,
                                          int bx, int by) {
  const int t = threadIdx.x;
  const int KT = K >> 5;
  const size_t tile = ((size_t)bx * KT + by) * (64 * 32);
  // 64*4 = 256 chunks, 256 threads -> one each
  const int c = t;
  const int mm = c >> 2, koct = (c & 3) * 8;
  const float* src = A + (size_t)(bx * 64 + mm) * K + by * 32 + koct;
  f32x4 f0 = *(const f32x4*)src;
  f32x4 f1 = *(const f32x4*)(src + 4);
  __align__(16) bf16 h[8];
  h[0]=(bf16)f0[0]; h[1]=(bf16)f0[1]; h[2]=(bf16)f0[2]; h[3]=(bf16)f0[3];
  h[4]=(bf16)f1[0]; h[5]=(bf16)f1[1]; h[6]=(bf16)f1[2]; h[7]=(bf16)f1[3];
  *(i32x4*)(Ap + tile + (size_t)c * 8) = *(const i32x4*)h;
}

// pack B (f32 [K][N] -> bf16 tiles [nt][kt][BNp][32]), BNp = 1<<bnsh
__device__ __forceinline__ void packB_dev(const float* __restrict__ B,
                                          bf16* __restrict__ Bp, int K, int N,
                                          int bnsh, int bx, int by,
                                          float* __restrict__ sLB) {
  const int BNp = 1 << bnsh, LS = BNp + 2;
  const int t = threadIdx.x;
  const int KT = K >> 5;
  for (int idx = t; idx < 32 * BNp; idx += 256) {
    const int kk = idx >> bnsh, nn = idx & (BNp - 1);
    sLB[kk * LS + nn] = B[(size_t)(by * 32 + kk) * N + bx * BNp + nn];
  }
  __syncthreads();
  const size_t tile = ((size_t)bx * KT + by) * ((size_t)BNp * 32);
  for (int c = t; c < BNp * 4; c += 256) {
    const int nn = c >> 2, koct = (c & 3) * 8;
    __align__(16) bf16 h[8];
#pragma unroll
    for (int j = 0; j < 8; ++j) h[j] = (bf16)sLB[(koct + j) * LS + nn];
    *(i32x4*)(Bp + tile + (size_t)c * 8) = *(const i32x4*)h;
  }
}

// embedding gather-sum -> cf[:,128:192]
__device__ __forceinline__ void embed_dev(const int* __restrict__ xs,
                                          const float* __restrict__ emb,
                                          float* __restrict__ cf, int blk) {
  const int wid = threadIdx.x >> 6, lane = threadIdx.x & 63;
  const int b = blk * 4 + wid;
  const int* row = xs + (size_t)b * 50;
  float acc = 0.f;
  for (int h = 0; h < 50; ++h) {
    int idx = row[h];
    acc += emb[(size_t)idx * 64 + lane];
  }
  cf[(size_t)b * 193 + 128 + lane] = acc;
}

// ---------------------------------------------------------------- fused prologue
// all independent prep work in one launch: tw1-pack(4648) + xep(1536) + xd(512)
// + pw1(96) + pw2(8) + bw1(64) + bw2(16) + tw2(256) + embed(1024) + pairs(1)
__global__ __launch_bounds__(256) void prologue_kernel(
    const float* __restrict__ xep, const float* __restrict__ xd,
    const float* __restrict__ pw1, const float* __restrict__ pw2,
    const float* __restrict__ bw1, const float* __restrict__ bw2,
    const float* __restrict__ tw1, const float* __restrict__ tw2,
    const int* __restrict__ xs, const float* __restrict__ emb,
    bf16* Xp, bf16* Xd, bf16* Bpw1, bf16* Bpw2, bf16* Bbw1, bf16* Bbw2,
    bf16* Btw1, bf16* Btw2, float* cf, int* pairs) {
  __shared__ float sLB[32 * 130];
  int i = blockIdx.x;
  if (i < 4648) { packB_dev(tw1, Btw1, 18592, 1024, 7, i & 7, i >> 3, sLB); return; }
  i -= 4648;
  if (i < 1536) { packA_dev(xep, Xp, 768, i & 63, i >> 6); return; }
  i -= 1536;
  if (i < 512)  { packA_dev(xd, Xd, 256, i & 63, i >> 6); return; }
  i -= 512;
  if (i < 96)   { packB_dev(pw1, Bpw1, 768, 256, 6, i & 3, i >> 2, sLB); return; }
  i -= 96;
  if (i < 8)    { packB_dev(pw2, Bpw2, 256, 64, 6, 0, i, sLB); return; }
  i -= 8;
  if (i < 64)   { packB_dev(bw1, Bbw1, 256, 512, 6, i & 7, i >> 3, sLB); return; }
  i -= 64;
  if (i < 16)   { packB_dev(bw2, Bbw2, 512, 64, 6, 0, i, sLB); return; }
  i -= 16;
  if (i < 256)  { packB_dev(tw2, Btw2, 1024, 512, 6, i & 7, i >> 3, sLB); return; }
  i -= 256;
  if (i < 1024) { embed_dev(xs, emb, cf, i); return; }
  i -= 1024;
  if (i == 0) pairs_dev(pairs);
}

// ================================================================ generic MFMA GEMM body (swizzled LDS)
template <int BM, int BN, int MF, int NF>
__device__ __forceinline__ void gemm_body(
    const bf16* __restrict__ Ap, const bf16* __restrict__ Bp,
    const float* __restrict__ bias,
    float* __restrict__ outF, int ldF,
    bf16* __restrict__ outP, int ktN, int bmsh,
    int KT, int M0, int relu_flag, int bx, int by,
    bf16* sA, bf16* sB) {
  const int t = threadIdx.x;
  const int wid = t >> 6, lane = t & 63;
  const int wm = (wid >> 1) * (MF * 16);
  const int wn = (wid & 1) * (NF * 16);
  const int r16 = lane & 15, q = lane >> 4;

  f32x4 acc[MF][NF];
#pragma unroll
  for (int i = 0; i < MF; ++i)
#pragma unroll
    for (int j = 0; j < NF; ++j) acc[i][j] = f32x4{0.f, 0.f, 0.f, 0.f};

  const bf16* aBase = Ap + (size_t)bx * KT * (BM * 32);
  const bf16* bBase = Bp + (size_t)by * KT * (BN * 32);
  constexpr int A_CH = BM * 4;
  constexpr int B_CH = BN * 4;

  for (int kt = 0; kt < KT; ++kt) {
    const bf16* ag = aBase + (size_t)kt * (BM * 32);
    const bf16* bg = bBase + (size_t)kt * (BN * 32);
#pragma unroll
    for (int c = t; c < A_CH; c += 256) {
      const int row = c >> 2, qs = c & 3, qg = (qs - (row >> 1)) & 3;
      async16(sA + c * 8, ag + row * 32 + qg * 8);
    }
#pragma unroll
    for (int c = t; c < B_CH; c += 256) {
      const int row = c >> 2, qs = c & 3, qg = (qs - (row >> 1)) & 3;
      async16(sB + c * 8, bg + row * 32 + qg * 8);
    }
    __syncthreads();
    v8bf af[MF], bfr[NF];
#pragma unroll
    for (int i = 0; i < MF; ++i) {
      const int row = wm + i * 16 + r16;
      af[i] = *(const v8bf*)(sA + row * 32 + (((q + (row >> 1)) & 3) * 8));
    }
#pragma unroll
    for (int j = 0; j < NF; ++j) {
      const int row = wn + j * 16 + r16;
      bfr[j] = *(const v8bf*)(sB + row * 32 + (((q + (row >> 1)) & 3) * 8));
    }
#pragma unroll
    for (int i = 0; i < MF; ++i)
#pragma unroll
      for (int j = 0; j < NF; ++j)
        acc[i][j] = __builtin_amdgcn_mfma_f32_16x16x32_bf16(af[i], bfr[j], acc[i][j], 0, 0, 0);
    __syncthreads();
  }

#pragma unroll
  for (int j = 0; j < NF; ++j) {
    const int gn = by * BN + wn + j * 16 + r16;
    const float bv = bias[gn];
#pragma unroll
    for (int i = 0; i < MF; ++i) {
      const int gm0 = M0 + bx * BM + wm + i * 16 + q * 4;
#pragma unroll
      for (int r = 0; r < 4; ++r) {
        float v = acc[i][j][r] + bv;
        if (relu_flag) v = fmaxf(v, 0.f);
        const int gm = gm0 + r;
        if (outF) outF[(size_t)gm * ldF + gn] = v;
        if (outP) {
          const int mt = gm >> bmsh, mm = gm & ((1 << bmsh) - 1);
          outP[(((size_t)mt * ktN + (gn >> 5)) << (bmsh + 5)) + ((size_t)mm << 5) + (gn & 31)] = (bf16)v;
        }
      }
    }
  }
}

template <int BM, int BN, int MF, int NF>
__global__ __launch_bounds__(256, 2) void gemm_kernel(
    const bf16* __restrict__ Ap, const bf16* __restrict__ Bp,
    const float* __restrict__ bias,
    float* __restrict__ outF, int ldF,
    bf16* __restrict__ outP, int ktN, int bmsh,
    int KT, int M0, int relu_flag) {
  __shared__ __align__(16) bf16 sA[BM * 32];
  __shared__ __align__(16) bf16 sB[BN * 32];
  gemm_body<BM, BN, MF, NF>(Ap, Bp, bias, outF, ldF, outP, ktN, bmsh,
                            KT, M0, relu_flag, blockIdx.x, blockIdx.y, sA, sB);
}

// two independent GEMMs in one launch, selected by blockIdx.z
template <int BM, int BN, int MF, int NF>
__global__ __launch_bounds__(256, 2) void gemm_dual_kernel(
    const bf16* Ap0, const bf16* Bp0, const float* bias0,
    float* outF0, int ldF0, bf16* outP0, int ktN0, int bmsh0, int KT0, int relu0, int gy0,
    const bf16* Ap1, const bf16* Bp1, const float* bias1,
    float* outF1, int ldF1, bf16* outP1, int ktN1, int bmsh1, int KT1, int relu1, int gy1) {
  __shared__ __align__(16) bf16 sA[BM * 32];
  __shared__ __align__(16) bf16 sB[BN * 32];
  if (blockIdx.z == 0) {
    if ((int)blockIdx.y >= gy0) return;
    gemm_body<BM, BN, MF, NF>(Ap0, Bp0, bias0, outF0, ldF0, outP0, ktN0, bmsh0,
                              KT0, 0, relu0, blockIdx.x, blockIdx.y, sA, sB);
  } else {
    if ((int)blockIdx.y >= gy1) return;
    gemm_body<BM, BN, MF, NF>(Ap1, Bp1, bias1, outF1, ldF1, outP1, ktN1, bmsh1,
                              KT1, 0, relu1, blockIdx.x, blockIdx.y, sA, sB);
  }
}

// ---------------------------------------------------------------- split-K MFMA GEMM -> bf16 partials [S][Mchunk][N]
// BK=64 double window: stage 2 k-tiles per barrier pair (halves barrier drains).
template <int BM, int BN, int MF, int NF>
__global__ __launch_bounds__(256, 2) void gemm_splitk_kernel(
    const bf16* __restrict__ Ap, const bf16* __restrict__ Bp,
    bf16* __restrict__ part, int KT, int S, int Mchunk, int N) {
  __shared__ __align__(16) bf16 sA[2][BM * 32];
  __shared__ __align__(16) bf16 sB[2][BN * 32];
  const int t = threadIdx.x;
  const int bx = blockIdx.x, by = blockIdx.y, bz = blockIdx.z;
  const int wid = t >> 6, lane = t & 63;
  const int wm = (wid >> 1) * (MF * 16);
  const int wn = (wid & 1) * (NF * 16);
  const int r16 = lane & 15, q = lane >> 4;
  const int kt0 = (KT * bz) / S, kt1 = (KT * (bz + 1)) / S;

  f32x4 acc[MF][NF];
#pragma unroll
  for (int i = 0; i < MF; ++i)
#pragma unroll
    for (int j = 0; j < NF; ++j) acc[i][j] = f32x4{0.f, 0.f, 0.f, 0.f};

  const bf16* aBase = Ap + (size_t)bx * KT * (BM * 32);
  const bf16* bBase = Bp + (size_t)by * KT * (BN * 32);
  constexpr int A_CH = BM * 4;
  constexpr int B_CH = BN * 4;

  auto stage = [&](int buf, int kt) {
    const bf16* ag = aBase + (size_t)kt * (BM * 32);
    const bf16* bg = bBase + (size_t)kt * (BN * 32);
#pragma unroll
    for (int c = t; c < A_CH; c += 256) {
      const int row = c >> 2, qs = c & 3, qg = (qs - (row >> 1)) & 3;
      async16(sA[buf] + c * 8, ag + row * 32 + qg * 8);
    }
#pragma unroll
    for (int c = t; c < B_CH; c += 256) {
      const int row = c >> 2, qs = c & 3, qg = (qs - (row >> 1)) & 3;
      async16(sB[buf] + c * 8, bg + row * 32 + qg * 8);
    }
  };
  auto compute = [&](int buf) {
    v8bf af[MF], bfr[NF];
#pragma unroll
    for (int i = 0; i < MF; ++i) {
      const int row = wm + i * 16 + r16;
      af[i] = *(const v8bf*)(sA[buf] + row * 32 + (((q + (row >> 1)) & 3) * 8));
    }
#pragma unroll
    for (int j = 0; j < NF; ++j) {
      const int row = wn + j * 16 + r16;
      bfr[j] = *(const v8bf*)(sB[buf] + row * 32 + (((q + (row >> 1)) & 3) * 8));
    }
#pragma unroll
    for (int i = 0; i < MF; ++i)
#pragma unroll
      for (int j = 0; j < NF; ++j)
        acc[i][j] = __builtin_amdgcn_mfma_f32_16x16x32_bf16(af[i], bfr[j], acc[i][j], 0, 0, 0);
  };

  int kt = kt0;
  for (; kt + 1 < kt1; kt += 2) {
    stage(0, kt);
    stage(1, kt + 1);
    __syncthreads();
    compute(0);
    compute(1);
    __syncthreads();
  }
  if (kt < kt1) {
    stage(0, kt);
    __syncthreads();
    compute(0);
    __syncthreads();
  }

  bf16* pBase = part + (size_t)bz * Mchunk * N;
#pragma unroll
  for (int j = 0; j < NF; ++j) {
    const int gn = by * BN + wn + j * 16 + r16;
#pragma unroll
    for (int i = 0; i < MF; ++i) {
      const int gm0 = bx * BM + wm + i * 16 + q * 4;
#pragma unroll
      for (int r = 0; r < 4; ++r)
        pBase[(size_t)(gm0 + r) * N + gn] = (bf16)acc[i][j][r];
    }
  }
}

// ---------------------------------------------------------------- split-K reduce: sum S bf16 partials, +bias, relu, pack bf16 t1 (BM=64 layout)
__global__ __launch_bounds__(256) void reducek_kernel(const bf16* __restrict__ part,
                                                      const float* __restrict__ bias,
                                                      bf16* __restrict__ t1,
                                                      int S, int Mchunk, int M0) {
  const int idx = blockIdx.x * 256 + threadIdx.x;  // one 8-wide group per thread
  const int gm = idx >> 7;                          // [0, Mchunk)
  const int gn8 = (idx & 127) * 8;                  // N = 1024
  float v[8] = {0.f, 0.f, 0.f, 0.f, 0.f, 0.f, 0.f, 0.f};
  for (int s = 0; s < S; ++s) {
    v8bf p = *(const v8bf*)(part + ((size_t)s * Mchunk + gm) * 1024 + gn8);
#pragma unroll
    for (int r = 0; r < 8; ++r) v[r] += (float)p[r];
  }
  const f32x4 b0 = *(const f32x4*)(bias + gn8);
  const f32x4 b1 = *(const f32x4*)(bias + gn8 + 4);
  __align__(16) bf16 h[8];
#pragma unroll
  for (int r = 0; r < 4; ++r) h[r] = (bf16)fmaxf(v[r] + b0[r], 0.f);
#pragma unroll
  for (int r = 0; r < 4; ++r) h[4 + r] = (bf16)fmaxf(v[4 + r] + b1[r], 0.f);
  const int G = M0 + gm;
  const int mt = G >> 6, mm = G & 63, kt = gn8 >> 5;
  *(i32x4*)(t1 + (((size_t)mt * 32 + kt) << 11) + (mm << 5) + (gn8 & 31)) = *(const i32x4*)h;
}

// ---------------------------------------------------------------- batchnorm stats over z [4096][64]
__global__ __launch_bounds__(256) void bnstats_kernel(const float* __restrict__ z,
                                                      float* __restrict__ stats) {
  const int j = blockIdx.x, t = threadIdx.x;
  float s = 0.f, s2 = 0.f;
  for (int b = t; b < 4096; b += 256) {
    float v = z[(size_t)b * 64 + j];
    s += v; s2 += v * v;
  }
  __shared__ float sh[256], sh2[256];
  sh[t] = s; sh2[t] = s2;
  __syncthreads();
  for (int o = 128; o > 0; o >>= 1) {
    if (t < o) { sh[t] += sh[t + o]; sh2[t] += sh2[t + o]; }
    __syncthreads();
  }
  if (t == 0) {
    float mu = sh[0] * (1.f / 4096.f);
    float var = sh2[0] * (1.f / 4096.f) - mu * mu;
    stats[j] = mu;
    stats[64 + j] = rsqrtf(var + 1e-5f);
  }
}

// ---------------------------------------------------------------- normalize -> cf[:,64:128], d_out tail, cf[:,192]=1
__global__ __launch_bounds__(256) void cfbuild_kernel(const float* __restrict__ z,
                                                      const float* __restrict__ stats,
                                                      const float* __restrict__ gamma,
                                                      const float* __restrict__ beta,
                                                      float* __restrict__ cf,
                                                      float* __restrict__ dout) {
  const int wid = threadIdx.x >> 6, lane = threadIdx.x & 63;
  const int b = blockIdx.x * 4 + wid;
  const float mu = stats[lane], rstd = stats[64 + lane];
  const float xe = gamma[lane] * (z[(size_t)b * 64 + lane] - mu) * rstd + beta[lane];
  cf[(size_t)b * 193 + 64 + lane] = xe;
  dout[4096 + (size_t)b * 64 + lane] = xe;
  if (lane == 0) cf[(size_t)b * 193 + 192] = 1.f;
}

// ---------------------------------------------------------------- interaction A generation -> packed bf16 tiles (BM=128)
__global__ __launch_bounds__(256, 2) void agen_kernel(const float* __restrict__ cf,
                                                      const int* __restrict__ pairs,
                                                      bf16* __restrict__ Ap, int rowBase) {
  __shared__ float sCF[64 * 193];
  const int t = threadIdx.x;
  const int gRow0 = rowBase + blockIdx.x * 64;
  for (int i = t; i < 64 * 193; i += 256) sCF[i] = cf[(size_t)gRow0 * 193 + i];
  __syncthreads();
  const int kt0 = blockIdx.y * 73;
  const int kt1 = (kt0 + 73 < 581) ? (kt0 + 73) : 581;
  const int mm = t >> 2, qrt = t & 3;
  const int lmt = blockIdx.x >> 1;
  const int mmt = (blockIdx.x & 1) * 64 + mm;
  const float* myrow = sCF + mm * 193;
  for (int kt = kt0; kt < kt1; ++kt) {
    const int kb = kt * 32 + qrt * 8;
    __align__(16) bf16 h[8];
#pragma unroll
    for (int j = 0; j < 8; ++j) {
      const int pr = pairs[kb + j];
      h[j] = (bf16)(myrow[pr >> 16] * myrow[pr & 0xffff]);
    }
    *(i32x4*)(Ap + (((size_t)lmt * 581 + kt) * 128 + mmt) * 32 + qrt * 8) = *(const i32x4*)h;
  }
}

// ---------------------------------------------------------------- final dot (512->1) + sigmoid
__global__ __launch_bounds__(256) void topdot_kernel(const float* __restrict__ t2,
                                                     const float* __restrict__ w,
                                                     const float* __restrict__ b3,
                                                     float* __restrict__ dout) {
  const int wid = threadIdx.x >> 6, lane = threadIdx.x & 63;
  const int b = blockIdx.x * 4 + wid;
  const f32x4* row = (const f32x4*)(t2 + (size_t)b * 512);
  const f32x4* wv = (const f32x4*)w;
  float s = 0.f;
#pragma unroll
  for (int i = 0; i < 2; ++i) {
    f32x4 a = row[lane * 2 + i], c = wv[lane * 2 + i];
    s += a[0] * c[0] + a[1] * c[1] + a[2] * c[2] + a[3] * c[3];
  }
  for (int m = 32; m > 0; m >>= 1) s += __shfl_xor(s, m, 64);
  if (lane == 0) dout[b] = 1.f / (1.f + __expf(-(s + b3[0])));
}

// ================================================================ launch
extern "C" void kernel_launch(void* const* d_in, const int* in_sizes, int n_in,
                              void* d_out, int out_size, void* d_ws, size_t ws_size,
                              hipStream_t stream) {
  const int*   xs   = (const int*)  d_in[0];
  const float* xd   = (const float*)d_in[1];
  const float* xep  = (const float*)d_in[2];
  const float* emb  = (const float*)d_in[3];
  const float* pw1  = (const float*)d_in[4];
  const float* pb1  = (const float*)d_in[5];
  const float* pw2  = (const float*)d_in[6];
  const float* pb2  = (const float*)d_in[7];
  const float* gmma = (const float*)d_in[8];
  const float* beta = (const float*)d_in[9];
  const float* bw1  = (const float*)d_in[10];
  const float* bb1  = (const float*)d_in[11];
  const float* bw2  = (const float*)d_in[12];
  const float* bb2  = (const float*)d_in[13];
  const float* tw1  = (const float*)d_in[14];
  const float* tb1  = (const float*)d_in[15];
  const float* tw2  = (const float*)d_in[16];
  const float* tb2  = (const float*)d_in[17];
  const float* tw3  = (const float*)d_in[18];
  const float* tb3  = (const float*)d_in[19];
  float* out = (float*)d_out;

  uint8_t* base = (uint8_t*)d_ws;
  size_t off = 0;
  auto alloc = [&](size_t b) {
    void* p = base + off;
    off = (off + b + 511) & ~((size_t)511);
    return p;
  };
  int*  pairs = (int*) alloc((size_t)18592 * 4);
  bf16* Xp    = (bf16*)alloc((size_t)4096 * 768 * 2);
  bf16* Xd    = (bf16*)alloc((size_t)4096 * 256 * 2);
  bf16* Bpw1  = (bf16*)alloc((size_t)768 * 256 * 2);
  bf16* Bpw2  = (bf16*)alloc((size_t)256 * 64 * 2);
  bf16* Bbw1  = (bf16*)alloc((size_t)256 * 512 * 2);
  bf16* Bbw2  = (bf16*)alloc((size_t)512 * 64 * 2);
  bf16* Btw1  = (bf16*)alloc((size_t)18592 * 1024 * 2);
  bf16* Btw2  = (bf16*)alloc((size_t)1024 * 512 * 2);
  bf16* hbuf  = (bf16*)alloc((size_t)4096 * 256 * 2);
  float* z    = (float*)alloc((size_t)4096 * 64 * 4);
  float* stats= (float*)alloc((size_t)128 * 4);
  bf16* b0    = (bf16*)alloc((size_t)4096 * 512 * 2);
  float* cf   = (float*)alloc((size_t)4096 * 193 * 4);
  bf16* t1    = (bf16*)alloc((size_t)4096 * 1024 * 2);
  float* t2   = (float*)alloc((size_t)4096 * 512 * 4);
  size_t fixedEnd = off;

  // pick (chunk, S): bf16 partials. grid = (chunk/128)*8*S; want >= ~2048 blocks.
  int chunk = 512, S = 8;
  {
    const int candC[5] = {4096, 2048, 2048, 1024, 512};
    const int candS[5] = {8, 16, 8, 16, 8};
    for (int i = 0; i < 5; ++i) {
      size_t need = fixedEnd + (size_t)candC[i] * 18592 * 2 + 1024 +
                    (size_t)candS[i] * candC[i] * 1024 * 2 + 1024;
      if (need <= ws_size) { chunk = candC[i]; S = candS[i]; break; }
    }
  }
  bf16* ApBig = (bf16*)alloc((size_t)chunk * 18592 * 2);
  bf16* partK = (bf16*)alloc((size_t)S * chunk * 1024 * 2);

  // ---- fused prologue: all packs + embed + pairs (independent) ----
  prologue_kernel<<<8161, 256, 0, stream>>>(
      xep, xd, pw1, pw2, bw1, bw2, tw1, tw2, xs, emb,
      Xp, Xd, Bpw1, Bpw2, Bbw1, Bbw2, Btw1, Btw2, cf, pairs);

  // ---- dual1: proj1 (xep@pw1, N=256) || bot1 (xd@bw1, N=512) ----
  gemm_dual_kernel<64, 64, 2, 2><<<dim3(64, 8, 2), 256, 0, stream>>>(
      Xp, Bpw1, pb1, nullptr, 0, hbuf, 8, 6, 24, 1, 4,
      Xd, Bbw1, bb1, nullptr, 0, b0, 16, 6, 8, 1, 8);
  // ---- dual2: proj2 (h@pw2 -> z f32) || bot2 (b0@bw2 -> cf[:,0:64]) ----
  gemm_dual_kernel<64, 64, 2, 2><<<dim3(64, 1, 2), 256, 0, stream>>>(
      hbuf, Bpw2, pb2, z, 64, nullptr, 0, 0, 8, 0, 1,
      b0, Bbw2, bb2, cf, 193, nullptr, 0, 0, 16, 1, 1);

  bnstats_kernel<<<64, 256, 0, stream>>>(z, stats);
  cfbuild_kernel<<<1024, 256, 0, stream>>>(z, stats, gmma, beta, cf, out);

  // ---- interaction + big GEMM (split-K, bf16 partials) + reduce ----
  for (int c0 = 0; c0 < 4096; c0 += chunk) {
    agen_kernel<<<dim3(chunk / 64, 8), 256, 0, stream>>>(cf, pairs, ApBig, c0);
    gemm_splitk_kernel<128, 128, 4, 4><<<dim3(chunk / 128, 8, S), 256, 0, stream>>>(
        ApBig, Btw1, partK, 581, S, chunk, 1024);
    reducek_kernel<<<chunk / 2, 256, 0, stream>>>(partK, tb1, t1, S, chunk, c0);
  }

  // ---- top2: t2 = relu(t1@tw2+tb2) (f32 row-major), t1 packed BM=64 ----
  gemm_kernel<64, 64, 2, 2><<<dim3(64, 8), 256, 0, stream>>>(
      t1, Btw2, tb2, t2, 512, nullptr, 0, 0, 32, 0, 1);
  // ---- top3: sigmoid(t2@tw3+tb3) -> out[0:4096] ----
  topdot_kernel<<<1024, 256, 0, stream>>>(t2, tw3, tb3, out);
}

// Round 4
// 383.009 us; speedup vs baseline: 2.0487x; 1.2135x over previous
//
#include <hip/hip_runtime.h>
#include <hip/hip_bf16.h>
#include <cstdint>
#include <cstddef>

typedef __bf16 bf16;
typedef unsigned char u8;
typedef __bf16 v8bf  __attribute__((ext_vector_type(8)));
typedef float  f32x4 __attribute__((ext_vector_type(4)));
typedef float  f32x16 __attribute__((ext_vector_type(16)));
typedef int    i32x4 __attribute__((ext_vector_type(4)));
typedef int    v8i32 __attribute__((ext_vector_type(8)));

// ---------------------------------------------------------------- async copy
__device__ __forceinline__ void async16(void* lds, const void* g) {
  __builtin_amdgcn_global_load_lds(
      (const __attribute__((address_space(1))) unsigned int*)g,
      (__attribute__((address_space(3))) unsigned int*)lds, 16, 0, 0);
}

// LDS tiles XOR-swizzled: 16B chunk (row, qs) holds global quarter
// (qs - (row>>1)) & 3; reader uses (q + (row>>1)) & 3. [R2: verified 0 conflicts]

// Big GEMM runs MX fp8 (e4m3): K padded 18592->18624 = 291 windows of 64.
// A layout per lane: m = lane&31, k = (lane>>5)*32 + j (32 contiguous bytes).
// B pre-scaled by 2^5 at pack time; HW block scale 0x7A (=2^-5) undoes it.

// ================================================================ prologue device funcs
__device__ __forceinline__ void pairs_dev(int* __restrict__ pairs) {
  int r = threadIdx.x;
  if (r < 192) {
    int off = 192 * r - (r * (r - 1)) / 2;
    for (int c = r; c < 192; ++c) pairs[off + c - r] = (r << 16) | c;
  } else if (r == 192) {
    for (int j = 0; j < 64; ++j) pairs[18528 + j] = (j << 16) | 192;
  } else if (r == 193) {
    for (int j = 18592; j < 18624; ++j) pairs[j] = (192 << 16) | 192;  // pad (B=0 there)
  }
}

// pack A (f32 row-major -> bf16 tiles [mt][kt][64][32])
__device__ __forceinline__ void packA_dev(const float* __restrict__ A,
                                          bf16* __restrict__ Ap, int K,
                                          int bx, int by) {
  const int t = threadIdx.x;
  const int KT = K >> 5;
  const size_t tile = ((size_t)bx * KT + by) * (64 * 32);
  const int c = t;
  const int mm = c >> 2, koct = (c & 3) * 8;
  const float* src = A + (size_t)(bx * 64 + mm) * K + by * 32 + koct;
  f32x4 f0 = *(const f32x4*)src;
  f32x4 f1 = *(const f32x4*)(src + 4);
  __align__(16) bf16 h[8];
  h[0]=(bf16)f0[0]; h[1]=(bf16)f0[1]; h[2]=(bf16)f0[2]; h[3]=(bf16)f0[3];
  h[4]=(bf16)f1[0]; h[5]=(bf16)f1[1]; h[6]=(bf16)f1[2]; h[7]=(bf16)f1[3];
  *(i32x4*)(Ap + tile + (size_t)c * 8) = *(const i32x4*)h;
}

// pack B (f32 [K][N] -> bf16 tiles [nt][kt][64][32])
__device__ __forceinline__ void packB_dev(const float* __restrict__ B,
                                          bf16* __restrict__ Bp, int K, int N,
                                          int bx, int by,
                                          float* __restrict__ sLB) {
  const int BNp = 64, LS = 66;
  const int t = threadIdx.x;
  const int KT = K >> 5;
  for (int idx = t; idx < 32 * BNp; idx += 256) {
    const int kk = idx >> 6, nn = idx & 63;
    sLB[kk * LS + nn] = B[(size_t)(by * 32 + kk) * N + bx * BNp + nn];
  }
  __syncthreads();
  const size_t tile = ((size_t)bx * KT + by) * ((size_t)BNp * 32);
  for (int c = t; c < BNp * 4; c += 256) {
    const int nn = c >> 2, koct = (c & 3) * 8;
    __align__(16) bf16 h[8];
#pragma unroll
    for (int j = 0; j < 8; ++j) h[j] = (bf16)sLB[(koct + j) * LS + nn];
    *(i32x4*)(Bp + tile + (size_t)c * 8) = *(const i32x4*)h;
  }
}

// pack tw1 -> fp8 e4m3 tiles [nt 8][kw 291][n 128][k 64 bytes], values *32 (HW scale 2^-5)
__device__ __forceinline__ void packTw1_dev(const float* __restrict__ tw1,
                                            u8* __restrict__ Bp, int nt, int kw,
                                            float* __restrict__ sLB) {
  const int t = threadIdx.x;
  for (int idx = t; idx < 64 * 128; idx += 256) {
    const int kk = idx >> 7, nn = idx & 127;
    const int gk = kw * 64 + kk;
    sLB[kk * 130 + nn] = (gk < 18592) ? tw1[(size_t)gk * 1024 + nt * 128 + nn] * 32.f : 0.f;
  }
  __syncthreads();
  u8* tile = Bp + ((size_t)nt * 291 + kw) * 8192;
  for (int c = t; c < 512; c += 256) {
    const int nn = c >> 2, kb = (c & 3) * 16;
    i32x4 d;
#pragma unroll
    for (int g = 0; g < 4; ++g) {
      const float p0 = sLB[(kb + g * 4 + 0) * 130 + nn];
      const float p1 = sLB[(kb + g * 4 + 1) * 130 + nn];
      const float p2 = sLB[(kb + g * 4 + 2) * 130 + nn];
      const float p3 = sLB[(kb + g * 4 + 3) * 130 + nn];
      int r = __builtin_amdgcn_cvt_pk_fp8_f32(p0, p1, 0, false);
      r = __builtin_amdgcn_cvt_pk_fp8_f32(p2, p3, r, true);
      d[g] = r;
    }
    *(i32x4*)(tile + c * 16) = d;
  }
}

// embedding gather-sum -> cf[:,128:192]
__device__ __forceinline__ void embed_dev(const int* __restrict__ xs,
                                          const float* __restrict__ emb,
                                          float* __restrict__ cf, int blk) {
  const int wid = threadIdx.x >> 6, lane = threadIdx.x & 63;
  const int b = blk * 4 + wid;
  const int* row = xs + (size_t)b * 50;
  float acc = 0.f;
  for (int h = 0; h < 50; ++h) {
    int idx = row[h];
    acc += emb[(size_t)idx * 64 + lane];
  }
  cf[(size_t)b * 193 + 128 + lane] = acc;
}

// ---------------------------------------------------------------- fused prologue
// tw1fp8(2328) + xep(1536) + xd(512) + pw1(96) + pw2(8) + bw1(64) + bw2(16)
// + tw2(256) + embed(1024) + pairs(1) = 5841 blocks
__global__ __launch_bounds__(256) void prologue_kernel(
    const float* __restrict__ xep, const float* __restrict__ xd,
    const float* __restrict__ pw1, const float* __restrict__ pw2,
    const float* __restrict__ bw1, const float* __restrict__ bw2,
    const float* __restrict__ tw1, const float* __restrict__ tw2,
    const int* __restrict__ xs, const float* __restrict__ emb,
    bf16* Xp, bf16* Xd, bf16* Bpw1, bf16* Bpw2, bf16* Bbw1, bf16* Bbw2,
    u8* Btw1, bf16* Btw2, float* cf, int* pairs) {
  __shared__ float sLB[64 * 130];
  int i = blockIdx.x;
  if (i < 2328) { packTw1_dev(tw1, Btw1, i & 7, i >> 3, sLB); return; }
  i -= 2328;
  if (i < 1536) { packA_dev(xep, Xp, 768, i & 63, i >> 6); return; }
  i -= 1536;
  if (i < 512)  { packA_dev(xd, Xd, 256, i & 63, i >> 6); return; }
  i -= 512;
  if (i < 96)   { packB_dev(pw1, Bpw1, 768, 256, i & 3, i >> 2, sLB); return; }
  i -= 96;
  if (i < 8)    { packB_dev(pw2, Bpw2, 256, 64, 0, i, sLB); return; }
  i -= 8;
  if (i < 64)   { packB_dev(bw1, Bbw1, 256, 512, i & 7, i >> 3, sLB); return; }
  i -= 64;
  if (i < 16)   { packB_dev(bw2, Bbw2, 512, 64, 0, i, sLB); return; }
  i -= 16;
  if (i < 256)  { packB_dev(tw2, Btw2, 1024, 512, i & 7, i >> 3, sLB); return; }
  i -= 256;
  if (i < 1024) { embed_dev(xs, emb, cf, i); return; }
  i -= 1024;
  if (i == 0) pairs_dev(pairs);
}

// ================================================================ bf16 MFMA GEMM body (small GEMMs)
template <int BM, int BN, int MF, int NF>
__device__ __forceinline__ void gemm_body(
    const bf16* __restrict__ Ap, const bf16* __restrict__ Bp,
    const float* __restrict__ bias,
    float* __restrict__ outF, int ldF,
    bf16* __restrict__ outP, int ktN, int bmsh,
    int KT, int M0, int relu_flag, int bx, int by,
    bf16* sA, bf16* sB) {
  const int t = threadIdx.x;
  const int wid = t >> 6, lane = t & 63;
  const int wm = (wid >> 1) * (MF * 16);
  const int wn = (wid & 1) * (NF * 16);
  const int r16 = lane & 15, q = lane >> 4;

  f32x4 acc[MF][NF];
#pragma unroll
  for (int i = 0; i < MF; ++i)
#pragma unroll
    for (int j = 0; j < NF; ++j) acc[i][j] = f32x4{0.f, 0.f, 0.f, 0.f};

  const bf16* aBase = Ap + (size_t)bx * KT * (BM * 32);
  const bf16* bBase = Bp + (size_t)by * KT * (BN * 32);
  constexpr int A_CH = BM * 4;
  constexpr int B_CH = BN * 4;

  for (int kt = 0; kt < KT; ++kt) {
    const bf16* ag = aBase + (size_t)kt * (BM * 32);
    const bf16* bg = bBase + (size_t)kt * (BN * 32);
#pragma unroll
    for (int c = t; c < A_CH; c += 256) {
      const int row = c >> 2, qs = c & 3, qg = (qs - (row >> 1)) & 3;
      async16(sA + c * 8, ag + row * 32 + qg * 8);
    }
#pragma unroll
    for (int c = t; c < B_CH; c += 256) {
      const int row = c >> 2, qs = c & 3, qg = (qs - (row >> 1)) & 3;
      async16(sB + c * 8, bg + row * 32 + qg * 8);
    }
    __syncthreads();
    v8bf af[MF], bfr[NF];
#pragma unroll
    for (int i = 0; i < MF; ++i) {
      const int row = wm + i * 16 + r16;
      af[i] = *(const v8bf*)(sA + row * 32 + (((q + (row >> 1)) & 3) * 8));
    }
#pragma unroll
    for (int j = 0; j < NF; ++j) {
      const int row = wn + j * 16 + r16;
      bfr[j] = *(const v8bf*)(sB + row * 32 + (((q + (row >> 1)) & 3) * 8));
    }
#pragma unroll
    for (int i = 0; i < MF; ++i)
#pragma unroll
      for (int j = 0; j < NF; ++j)
        acc[i][j] = __builtin_amdgcn_mfma_f32_16x16x32_bf16(af[i], bfr[j], acc[i][j], 0, 0, 0);
    __syncthreads();
  }

#pragma unroll
  for (int j = 0; j < NF; ++j) {
    const int gn = by * BN + wn + j * 16 + r16;
    const float bv = bias[gn];
#pragma unroll
    for (int i = 0; i < MF; ++i) {
      const int gm0 = M0 + bx * BM + wm + i * 16 + q * 4;
#pragma unroll
      for (int r = 0; r < 4; ++r) {
        float v = acc[i][j][r] + bv;
        if (relu_flag) v = fmaxf(v, 0.f);
        const int gm = gm0 + r;
        if (outF) outF[(size_t)gm * ldF + gn] = v;
        if (outP) {
          const int mt = gm >> bmsh, mm = gm & ((1 << bmsh) - 1);
          outP[(((size_t)mt * ktN + (gn >> 5)) << (bmsh + 5)) + ((size_t)mm << 5) + (gn & 31)] = (bf16)v;
        }
      }
    }
  }
}

template <int BM, int BN, int MF, int NF>
__global__ __launch_bounds__(256, 2) void gemm_kernel(
    const bf16* __restrict__ Ap, const bf16* __restrict__ Bp,
    const float* __restrict__ bias,
    float* __restrict__ outF, int ldF,
    bf16* __restrict__ outP, int ktN, int bmsh,
    int KT, int M0, int relu_flag) {
  __shared__ __align__(16) bf16 sA[BM * 32];
  __shared__ __align__(16) bf16 sB[BN * 32];
  gemm_body<BM, BN, MF, NF>(Ap, Bp, bias, outF, ldF, outP, ktN, bmsh,
                            KT, M0, relu_flag, blockIdx.x, blockIdx.y, sA, sB);
}

template <int BM, int BN, int MF, int NF>
__global__ __launch_bounds__(256, 2) void gemm_dual_kernel(
    const bf16* Ap0, const bf16* Bp0, const float* bias0,
    float* outF0, int ldF0, bf16* outP0, int ktN0, int bmsh0, int KT0, int relu0, int gy0,
    const bf16* Ap1, const bf16* Bp1, const float* bias1,
    float* outF1, int ldF1, bf16* outP1, int ktN1, int bmsh1, int KT1, int relu1, int gy1) {
  __shared__ __align__(16) bf16 sA[BM * 32];
  __shared__ __align__(16) bf16 sB[BN * 32];
  if (blockIdx.z == 0) {
    if ((int)blockIdx.y >= gy0) return;
    gemm_body<BM, BN, MF, NF>(Ap0, Bp0, bias0, outF0, ldF0, outP0, ktN0, bmsh0,
                              KT0, 0, relu0, blockIdx.x, blockIdx.y, sA, sB);
  } else {
    if ((int)blockIdx.y >= gy1) return;
    gemm_body<BM, BN, MF, NF>(Ap1, Bp1, bias1, outF1, ldF1, outP1, ktN1, bmsh1,
                              KT1, 0, relu1, blockIdx.x, blockIdx.y, sA, sB);
  }
}

// ---------------------------------------------------------------- MX fp8 split-K GEMM -> bf16 partials [S][Mchunk][1024]
// 128x128 tile, 4 waves (2x2), per-wave 2x2 of 32x32x64 scaled MFMA. K window = 64 B.
__global__ __launch_bounds__(256, 2) void gemm_splitk_mx(
    const u8* __restrict__ Ap, const u8* __restrict__ Bp,
    bf16* __restrict__ part, int S, int Mchunk) {
  __shared__ __align__(16) u8 sA[2][8192];
  __shared__ __align__(16) u8 sB[2][8192];
  const int t = threadIdx.x;
  const int bx = blockIdx.x, by = blockIdx.y, bz = blockIdx.z;
  const int wid = t >> 6, lane = t & 63;
  const int wm = (wid >> 1) * 64, wn = (wid & 1) * 64;
  const int l31 = lane & 31, khalf = lane >> 5;
  const int kw0 = (291 * bz) / S, kw1 = (291 * (bz + 1)) / S;

  f32x16 acc[2][2];
#pragma unroll
  for (int i = 0; i < 2; ++i)
#pragma unroll
    for (int j = 0; j < 2; ++j)
#pragma unroll
      for (int r = 0; r < 16; ++r) acc[i][j][r] = 0.f;

  const u8* aBase = Ap + (size_t)bx * 291 * 8192;
  const u8* bBase = Bp + (size_t)by * 291 * 8192;

  auto stage = [&](int buf, int kw) {
    const u8* ag = aBase + (size_t)kw * 8192;
    const u8* bg = bBase + (size_t)kw * 8192;
#pragma unroll
    for (int c = t; c < 512; c += 256) {
      const int row = c >> 2, qs = c & 3, qg = (qs - (row >> 1)) & 3;
      async16(sA[buf] + c * 16, ag + row * 64 + qg * 16);
    }
#pragma unroll
    for (int c = t; c < 512; c += 256) {
      const int row = c >> 2, qs = c & 3, qg = (qs - (row >> 1)) & 3;
      async16(sB[buf] + c * 16, bg + row * 64 + qg * 16);
    }
  };
  auto frag = [&](const u8* s, int row) -> v8i32 {
    const int q0 = (khalf * 2 + (row >> 1)) & 3;
    const int q1 = (khalf * 2 + 1 + (row >> 1)) & 3;
    union { i32x4 h[2]; v8i32 v; } u;
    u.h[0] = *(const i32x4*)(s + row * 64 + q0 * 16);
    u.h[1] = *(const i32x4*)(s + row * 64 + q1 * 16);
    return u.v;
  };
  auto compute = [&](int buf) {
    v8i32 av[2], bv[2];
#pragma unroll
    for (int i = 0; i < 2; ++i) av[i] = frag(sA[buf], wm + i * 32 + l31);
#pragma unroll
    for (int j = 0; j < 2; ++j) bv[j] = frag(sB[buf], wn + j * 32 + l31);
#pragma unroll
    for (int i = 0; i < 2; ++i)
#pragma unroll
      for (int j = 0; j < 2; ++j)
        acc[i][j] = __builtin_amdgcn_mfma_scale_f32_32x32x64_f8f6f4(
            av[i], bv[j], acc[i][j], 0, 0,
            0, 0x7F7F7F7F,   // A scale: 2^0
            0, 0x7A7A7A7A);  // B scale: 2^-5 (undo the *32 pack)
  };

  int kw = kw0;
  for (; kw + 1 < kw1; kw += 2) {
    stage(0, kw);
    stage(1, kw + 1);
    __syncthreads();
    compute(0);
    compute(1);
    __syncthreads();
  }
  if (kw < kw1) {
    stage(0, kw);
    __syncthreads();
    compute(0);
    __syncthreads();
  }

  bf16* pBase = part + (size_t)bz * Mchunk * 1024;
#pragma unroll
  for (int i = 0; i < 2; ++i)
#pragma unroll
    for (int j = 0; j < 2; ++j) {
      const int gn = by * 128 + wn + j * 32 + l31;
#pragma unroll
      for (int r = 0; r < 16; ++r) {
        const int gm = bx * 128 + wm + i * 32 + (r & 3) + 8 * (r >> 2) + 4 * khalf;
        pBase[(size_t)gm * 1024 + gn] = (bf16)acc[i][j][r];
      }
    }
}

// ---------------------------------------------------------------- split-K reduce -> t1 packed bf16 (BM=64)
__global__ __launch_bounds__(256) void reducek_kernel(const bf16* __restrict__ part,
                                                      const float* __restrict__ bias,
                                                      bf16* __restrict__ t1,
                                                      int S, int Mchunk, int M0) {
  const int idx = blockIdx.x * 256 + threadIdx.x;
  const int gm = idx >> 7;
  const int gn8 = (idx & 127) * 8;
  float v[8] = {0.f, 0.f, 0.f, 0.f, 0.f, 0.f, 0.f, 0.f};
  for (int s = 0; s < S; ++s) {
    v8bf p = *(const v8bf*)(part + ((size_t)s * Mchunk + gm) * 1024 + gn8);
#pragma unroll
    for (int r = 0; r < 8; ++r) v[r] += (float)p[r];
  }
  const f32x4 b0 = *(const f32x4*)(bias + gn8);
  const f32x4 b1 = *(const f32x4*)(bias + gn8 + 4);
  __align__(16) bf16 h[8];
#pragma unroll
  for (int r = 0; r < 4; ++r) h[r] = (bf16)fmaxf(v[r] + b0[r], 0.f);
#pragma unroll
  for (int r = 0; r < 4; ++r) h[4 + r] = (bf16)fmaxf(v[4 + r] + b1[r], 0.f);
  const int G = M0 + gm;
  const int mt = G >> 6, mm = G & 63, kt = gn8 >> 5;
  *(i32x4*)(t1 + (((size_t)mt * 32 + kt) << 11) + (mm << 5) + (gn8 & 31)) = *(const i32x4*)h;
}

// ---------------------------------------------------------------- batchnorm stats
__global__ __launch_bounds__(256) void bnstats_kernel(const float* __restrict__ z,
                                                      float* __restrict__ stats) {
  const int j = blockIdx.x, t = threadIdx.x;
  float s = 0.f, s2 = 0.f;
  for (int b = t; b < 4096; b += 256) {
    float v = z[(size_t)b * 64 + j];
    s += v; s2 += v * v;
  }
  __shared__ float sh[256], sh2[256];
  sh[t] = s; sh2[t] = s2;
  __syncthreads();
  for (int o = 128; o > 0; o >>= 1) {
    if (t < o) { sh[t] += sh[t + o]; sh2[t] += sh2[t + o]; }
    __syncthreads();
  }
  if (t == 0) {
    float mu = sh[0] * (1.f / 4096.f);
    float var = sh2[0] * (1.f / 4096.f) - mu * mu;
    stats[j] = mu;
    stats[64 + j] = rsqrtf(var + 1e-5f);
  }
}

// ---------------------------------------------------------------- normalize -> cf[:,64:128], d_out tail, cf[:,192]=1
__global__ __launch_bounds__(256) void cfbuild_kernel(const float* __restrict__ z,
                                                      const float* __restrict__ stats,
                                                      const float* __restrict__ gamma,
                                                      const float* __restrict__ beta,
                                                      float* __restrict__ cf,
                                                      float* __restrict__ dout) {
  const int wid = threadIdx.x >> 6, lane = threadIdx.x & 63;
  const int b = blockIdx.x * 4 + wid;
  const float mu = stats[lane], rstd = stats[64 + lane];
  const float xe = gamma[lane] * (z[(size_t)b * 64 + lane] - mu) * rstd + beta[lane];
  cf[(size_t)b * 193 + 64 + lane] = xe;
  dout[4096 + (size_t)b * 64 + lane] = xe;
  if (lane == 0) cf[(size_t)b * 193 + 192] = 1.f;
}

// ---------------------------------------------------------------- interaction A -> fp8 tiles [mt][kw 291][128][64]
__global__ __launch_bounds__(256, 2) void agen_kernel(const float* __restrict__ cf,
                                                      const int* __restrict__ pairs,
                                                      u8* __restrict__ Ap, int rowBase) {
  __shared__ float sCF[64 * 193];
  const int t = threadIdx.x;
  const int gRow0 = rowBase + blockIdx.x * 64;
  for (int i = t; i < 64 * 193; i += 256) sCF[i] = cf[(size_t)gRow0 * 193 + i];
  __syncthreads();
  const int kw0 = (291 * blockIdx.y) / 8;
  const int kw1 = (291 * (blockIdx.y + 1)) / 8;
  const int row = t >> 2, kq = t & 3;
  const int mt = blockIdx.x >> 1;
  const int mrow = (blockIdx.x & 1) * 64 + row;
  const float* myrow = sCF + row * 193;
  for (int kw = kw0; kw < kw1; ++kw) {
    const int kb = kw * 64 + kq * 16;
    i32x4 d;
#pragma unroll
    for (int g = 0; g < 4; ++g) {
      float p[4];
#pragma unroll
      for (int j = 0; j < 4; ++j) {
        const int pr = pairs[kb + g * 4 + j];
        p[j] = myrow[pr >> 16] * myrow[pr & 0xffff];
      }
      int r = __builtin_amdgcn_cvt_pk_fp8_f32(p[0], p[1], 0, false);
      r = __builtin_amdgcn_cvt_pk_fp8_f32(p[2], p[3], r, true);
      d[g] = r;
    }
    *(i32x4*)(Ap + (((size_t)mt * 291 + kw) * 128 + mrow) * 64 + kq * 16) = d;
  }
}

// ---------------------------------------------------------------- final dot (512->1) + sigmoid
__global__ __launch_bounds__(256) void topdot_kernel(const float* __restrict__ t2,
                                                     const float* __restrict__ w,
                                                     const float* __restrict__ b3,
                                                     float* __restrict__ dout) {
  const int wid = threadIdx.x >> 6, lane = threadIdx.x & 63;
  const int b = blockIdx.x * 4 + wid;
  const f32x4* row = (const f32x4*)(t2 + (size_t)b * 512);
  const f32x4* wv = (const f32x4*)w;
  float s = 0.f;
#pragma unroll
  for (int i = 0; i < 2; ++i) {
    f32x4 a = row[lane * 2 + i], c = wv[lane * 2 + i];
    s += a[0] * c[0] + a[1] * c[1] + a[2] * c[2] + a[3] * c[3];
  }
  for (int m = 32; m > 0; m >>= 1) s += __shfl_xor(s, m, 64);
  if (lane == 0) dout[b] = 1.f / (1.f + __expf(-(s + b3[0])));
}

// ================================================================ launch
extern "C" void kernel_launch(void* const* d_in, const int* in_sizes, int n_in,
                              void* d_out, int out_size, void* d_ws, size_t ws_size,
                              hipStream_t stream) {
  const int*   xs   = (const int*)  d_in[0];
  const float* xd   = (const float*)d_in[1];
  const float* xep  = (const float*)d_in[2];
  const float* emb  = (const float*)d_in[3];
  const float* pw1  = (const float*)d_in[4];
  const float* pb1  = (const float*)d_in[5];
  const float* pw2  = (const float*)d_in[6];
  const float* pb2  = (const float*)d_in[7];
  const float* gmma = (const float*)d_in[8];
  const float* beta = (const float*)d_in[9];
  const float* bw1  = (const float*)d_in[10];
  const float* bb1  = (const float*)d_in[11];
  const float* bw2  = (const float*)d_in[12];
  const float* bb2  = (const float*)d_in[13];
  const float* tw1  = (const float*)d_in[14];
  const float* tb1  = (const float*)d_in[15];
  const float* tw2  = (const float*)d_in[16];
  const float* tb2  = (const float*)d_in[17];
  const float* tw3  = (const float*)d_in[18];
  const float* tb3  = (const float*)d_in[19];
  float* out = (float*)d_out;

  uint8_t* base = (uint8_t*)d_ws;
  size_t off = 0;
  auto alloc = [&](size_t b) {
    void* p = base + off;
    off = (off + b + 511) & ~((size_t)511);
    return p;
  };
  int*  pairs = (int*) alloc((size_t)18624 * 4);
  bf16* Xp    = (bf16*)alloc((size_t)4096 * 768 * 2);
  bf16* Xd    = (bf16*)alloc((size_t)4096 * 256 * 2);
  bf16* Bpw1  = (bf16*)alloc((size_t)768 * 256 * 2);
  bf16* Bpw2  = (bf16*)alloc((size_t)256 * 64 * 2);
  bf16* Bbw1  = (bf16*)alloc((size_t)256 * 512 * 2);
  bf16* Bbw2  = (bf16*)alloc((size_t)512 * 64 * 2);
  u8*   Btw1  = (u8*)  alloc((size_t)8 * 291 * 8192);      // fp8 tiles
  bf16* Btw2  = (bf16*)alloc((size_t)1024 * 512 * 2);
  bf16* hbuf  = (bf16*)alloc((size_t)4096 * 256 * 2);
  float* z    = (float*)alloc((size_t)4096 * 64 * 4);
  float* stats= (float*)alloc((size_t)128 * 4);
  bf16* b0    = (bf16*)alloc((size_t)4096 * 512 * 2);
  float* cf   = (float*)alloc((size_t)4096 * 193 * 4);
  bf16* t1    = (bf16*)alloc((size_t)4096 * 1024 * 2);
  float* t2   = (float*)alloc((size_t)4096 * 512 * 4);
  size_t fixedEnd = off;

  // pick (chunk, S): Ap fp8 = chunk*18624 B; partK bf16 = S*chunk*1024*2 B
  int chunk = 512, S = 8;
  {
    const int candC[5] = {4096, 4096, 2048, 1024, 512};
    const int candS[5] = {8, 4, 8, 8, 8};
    for (int i = 0; i < 5; ++i) {
      size_t need = fixedEnd + (size_t)candC[i] * 18624 + 1024 +
                    (size_t)candS[i] * candC[i] * 1024 * 2 + 1024;
      if (need <= ws_size) { chunk = candC[i]; S = candS[i]; break; }
    }
  }
  u8*   ApBig = (u8*)  alloc((size_t)chunk * 18624);
  bf16* partK = (bf16*)alloc((size_t)S * chunk * 1024 * 2);

  // ---- fused prologue ----
  prologue_kernel<<<5841, 256, 0, stream>>>(
      xep, xd, pw1, pw2, bw1, bw2, tw1, tw2, xs, emb,
      Xp, Xd, Bpw1, Bpw2, Bbw1, Bbw2, Btw1, Btw2, cf, pairs);

  // ---- dual1: proj1 (xep@pw1, N=256) || bot1 (xd@bw1, N=512) ----
  gemm_dual_kernel<64, 64, 2, 2><<<dim3(64, 8, 2), 256, 0, stream>>>(
      Xp, Bpw1, pb1, nullptr, 0, hbuf, 8, 6, 24, 1, 4,
      Xd, Bbw1, bb1, nullptr, 0, b0, 16, 6, 8, 1, 8);
  // ---- dual2: proj2 (h@pw2 -> z f32) || bot2 (b0@bw2 -> cf[:,0:64]) ----
  gemm_dual_kernel<64, 64, 2, 2><<<dim3(64, 1, 2), 256, 0, stream>>>(
      hbuf, Bpw2, pb2, z, 64, nullptr, 0, 0, 8, 0, 1,
      b0, Bbw2, bb2, cf, 193, nullptr, 0, 0, 16, 1, 1);

  bnstats_kernel<<<64, 256, 0, stream>>>(z, stats);
  cfbuild_kernel<<<1024, 256, 0, stream>>>(z, stats, gmma, beta, cf, out);

  // ---- interaction (fp8) + MX split-K GEMM + reduce ----
  for (int c0 = 0; c0 < 4096; c0 += chunk) {
    agen_kernel<<<dim3(chunk / 64, 8), 256, 0, stream>>>(cf, pairs, ApBig, c0);
    gemm_splitk_mx<<<dim3(chunk / 128, 8, S), 256, 0, stream>>>(
        ApBig, Btw1, partK, S, chunk);
    reducek_kernel<<<chunk / 2, 256, 0, stream>>>(partK, tb1, t1, S, chunk, c0);
  }

  // ---- top2: t2 = relu(t1@tw2+tb2) ----
  gemm_kernel<64, 64, 2, 2><<<dim3(64, 8), 256, 0, stream>>>(
      t1, Btw2, tb2, t2, 512, nullptr, 0, 0, 32, 0, 1);
  // ---- top3: sigmoid(t2@tw3+tb3) -> out[0:4096] ----
  topdot_kernel<<<1024, 256, 0, stream>>>(t2, tw3, tb3, out);
}

// Round 5
// 360.571 us; speedup vs baseline: 2.1762x; 1.0622x over previous
//
#include <hip/hip_runtime.h>
#include <hip/hip_bf16.h>
#include <cstdint>
#include <cstddef>

typedef __bf16 bf16;
typedef unsigned char u8;
typedef unsigned short u16;
typedef __bf16 v8bf  __attribute__((ext_vector_type(8)));
typedef float  f32x4 __attribute__((ext_vector_type(4)));
typedef float  f32x16 __attribute__((ext_vector_type(16)));
typedef int    i32x4 __attribute__((ext_vector_type(4)));
typedef int    v8i32 __attribute__((ext_vector_type(8)));

// ---------------------------------------------------------------- async copy
__device__ __forceinline__ void async16(void* lds, const void* g) {
  __builtin_amdgcn_global_load_lds(
      (const __attribute__((address_space(1))) unsigned int*)g,
      (__attribute__((address_space(3))) unsigned int*)lds, 16, 0, 0);
}

// LDS tiles XOR-swizzled at 16B/8B quarter granularity (R2: bf16 conflicts ->0;
// fp8 64-B rows keep an inherent 4-way residual — pigeonhole at quarter level).

// Big GEMM: MX fp8 e4m3, K padded 18592->18624 = 291 windows of 64.
// B pre-scaled by 2^5 at pack; HW block scale 0x7A (=2^-5) undoes it.

// ================================================================ prologue device funcs
__device__ __forceinline__ void pairs_dev(u16* __restrict__ pairs) {
  int r = threadIdx.x;
  if (r < 192) {
    int off = 192 * r - (r * (r - 1)) / 2;
    for (int c = r; c < 192; ++c) pairs[off + c - r] = (u16)((r << 8) | c);
  } else if (r == 192) {
    for (int j = 0; j < 64; ++j) pairs[18528 + j] = (u16)((j << 8) | 192);
  } else if (r == 193) {
    for (int j = 18592; j < 18624; ++j) pairs[j] = (u16)((192 << 8) | 192);  // pad (B=0)
  }
}

// pack A (f32 row-major -> bf16 tiles [mt][kt][64][32])
__device__ __forceinline__ void packA_dev(const float* __restrict__ A,
                                          bf16* __restrict__ Ap, int K,
                                          int bx, int by) {
  const int t = threadIdx.x;
  const int KT = K >> 5;
  const size_t tile = ((size_t)bx * KT + by) * (64 * 32);
  const int c = t;
  const int mm = c >> 2, koct = (c & 3) * 8;
  const float* src = A + (size_t)(bx * 64 + mm) * K + by * 32 + koct;
  f32x4 f0 = *(const f32x4*)src;
  f32x4 f1 = *(const f32x4*)(src + 4);
  __align__(16) bf16 h[8];
  h[0]=(bf16)f0[0]; h[1]=(bf16)f0[1]; h[2]=(bf16)f0[2]; h[3]=(bf16)f0[3];
  h[4]=(bf16)f1[0]; h[5]=(bf16)f1[1]; h[6]=(bf16)f1[2]; h[7]=(bf16)f1[3];
  *(i32x4*)(Ap + tile + (size_t)c * 8) = *(const i32x4*)h;
}

// pack B (f32 [K][N] -> bf16 tiles [nt][kt][64][32])
__device__ __forceinline__ void packB_dev(const float* __restrict__ B,
                                          bf16* __restrict__ Bp, int K, int N,
                                          int bx, int by,
                                          float* __restrict__ sLB) {
  const int BNp = 64, LS = 66;
  const int t = threadIdx.x;
  const int KT = K >> 5;
  for (int idx = t; idx < 32 * BNp; idx += 256) {
    const int kk = idx >> 6, nn = idx & 63;
    sLB[kk * LS + nn] = B[(size_t)(by * 32 + kk) * N + bx * BNp + nn];
  }
  __syncthreads();
  const size_t tile = ((size_t)bx * KT + by) * ((size_t)BNp * 32);
  for (int c = t; c < BNp * 4; c += 256) {
    const int nn = c >> 2, koct = (c & 3) * 8;
    __align__(16) bf16 h[8];
#pragma unroll
    for (int j = 0; j < 8; ++j) h[j] = (bf16)sLB[(koct + j) * LS + nn];
    *(i32x4*)(Bp + tile + (size_t)c * 8) = *(const i32x4*)h;
  }
}

// pack tw1 -> fp8 e4m3 tiles [nt 8][kw 291][n 128][k 64 bytes], values *32.
// Two phases of 32 k-rows: f32x4 vectorized loads, 16.9 KB LDS.
__device__ __forceinline__ void packTw1_dev(const float* __restrict__ tw1,
                                            u8* __restrict__ Bp, int nt, int kw,
                                            float* __restrict__ sLB) {
  const int t = threadIdx.x;
  u8* tile = Bp + ((size_t)nt * 291 + kw) * 8192;
#pragma unroll
  for (int ph = 0; ph < 2; ++ph) {
    if (ph) __syncthreads();
#pragma unroll
    for (int idx = t; idx < 1024; idx += 256) {
      const int kk = idx >> 5, nn4 = (idx & 31) * 4;
      const int gk = kw * 64 + ph * 32 + kk;
      f32x4 v = f32x4{0.f, 0.f, 0.f, 0.f};
      if (gk < 18592) {
        v = *(const f32x4*)(tw1 + (size_t)gk * 1024 + nt * 128 + nn4);
        v *= 32.f;
      }
      *(f32x4*)(sLB + kk * 132 + nn4) = v;
    }
    __syncthreads();
    // 256 output chunks this phase, one per thread
    const int nn = t >> 1;
    const int hkb = (t & 1) * 16;
    const int c = nn * 4 + ph * 2 + (t & 1);
    i32x4 d;
#pragma unroll
    for (int g = 0; g < 4; ++g) {
      const float p0 = sLB[(hkb + g * 4 + 0) * 132 + nn];
      const float p1 = sLB[(hkb + g * 4 + 1) * 132 + nn];
      const float p2 = sLB[(hkb + g * 4 + 2) * 132 + nn];
      const float p3 = sLB[(hkb + g * 4 + 3) * 132 + nn];
      int r = __builtin_amdgcn_cvt_pk_fp8_f32(p0, p1, 0, false);
      r = __builtin_amdgcn_cvt_pk_fp8_f32(p2, p3, r, true);
      d[g] = r;
    }
    *(i32x4*)(tile + c * 16) = d;
  }
}

// ---------------------------------------------------------------- fused prologue
// tw1fp8(2328) + xep(1536) + xd(512) + pw1(96) + pw2(8) + bw1(64) + bw2(16)
// + tw2(256) + pairs(1) = 4817 blocks. (embed moved to dual1 z=2)
__global__ __launch_bounds__(256) void prologue_kernel(
    const float* __restrict__ xep, const float* __restrict__ xd,
    const float* __restrict__ pw1, const float* __restrict__ pw2,
    const float* __restrict__ bw1, const float* __restrict__ bw2,
    const float* __restrict__ tw1, const float* __restrict__ tw2,
    bf16* Xp, bf16* Xd, bf16* Bpw1, bf16* Bpw2, bf16* Bbw1, bf16* Bbw2,
    u8* Btw1, bf16* Btw2, u16* pairs) {
  __shared__ float sLB[32 * 132];
  int i = blockIdx.x;
  if (i < 2328) { packTw1_dev(tw1, Btw1, i & 7, i >> 3, sLB); return; }
  i -= 2328;
  if (i < 1536) { packA_dev(xep, Xp, 768, i & 63, i >> 6); return; }
  i -= 1536;
  if (i < 512)  { packA_dev(xd, Xd, 256, i & 63, i >> 6); return; }
  i -= 512;
  if (i < 96)   { packB_dev(pw1, Bpw1, 768, 256, i & 3, i >> 2, sLB); return; }
  i -= 96;
  if (i < 8)    { packB_dev(pw2, Bpw2, 256, 64, 0, i, sLB); return; }
  i -= 8;
  if (i < 64)   { packB_dev(bw1, Bbw1, 256, 512, i & 7, i >> 3, sLB); return; }
  i -= 64;
  if (i < 16)   { packB_dev(bw2, Bbw2, 512, 64, 0, i, sLB); return; }
  i -= 16;
  if (i < 256)  { packB_dev(tw2, Btw2, 1024, 512, i & 7, i >> 3, sLB); return; }
  i -= 256;
  if (i == 0) pairs_dev(pairs);
}

// embedding gather-sum -> cf[:,128:192], 8 rows per block
__device__ __forceinline__ void embed8_dev(const int* __restrict__ xs,
                                           const float* __restrict__ emb,
                                           float* __restrict__ cf, int blk) {
  const int wid = threadIdx.x >> 6, lane = threadIdx.x & 63;
#pragma unroll
  for (int s = 0; s < 2; ++s) {
    const int b = blk * 8 + s * 4 + wid;
    const int* row = xs + (size_t)b * 50;
    float acc = 0.f;
    for (int h = 0; h < 50; ++h) {
      int idx = row[h];
      acc += emb[(size_t)idx * 64 + lane];
    }
    cf[(size_t)b * 193 + 128 + lane] = acc;
  }
}

// ================================================================ bf16 MFMA GEMM body (small GEMMs)
template <int BM, int BN, int MF, int NF>
__device__ __forceinline__ void gemm_body(
    const bf16* __restrict__ Ap, const bf16* __restrict__ Bp,
    const float* __restrict__ bias,
    float* __restrict__ outF, int ldF,
    bf16* __restrict__ outP, int ktN, int bmsh,
    int KT, int M0, int relu_flag, int bx, int by,
    bf16* sA, bf16* sB) {
  const int t = threadIdx.x;
  const int wid = t >> 6, lane = t & 63;
  const int wm = (wid >> 1) * (MF * 16);
  const int wn = (wid & 1) * (NF * 16);
  const int r16 = lane & 15, q = lane >> 4;

  f32x4 acc[MF][NF];
#pragma unroll
  for (int i = 0; i < MF; ++i)
#pragma unroll
    for (int j = 0; j < NF; ++j) acc[i][j] = f32x4{0.f, 0.f, 0.f, 0.f};

  const bf16* aBase = Ap + (size_t)bx * KT * (BM * 32);
  const bf16* bBase = Bp + (size_t)by * KT * (BN * 32);
  constexpr int A_CH = BM * 4;
  constexpr int B_CH = BN * 4;

  for (int kt = 0; kt < KT; ++kt) {
    const bf16* ag = aBase + (size_t)kt * (BM * 32);
    const bf16* bg = bBase + (size_t)kt * (BN * 32);
#pragma unroll
    for (int c = t; c < A_CH; c += 256) {
      const int row = c >> 2, qs = c & 3, qg = (qs - (row >> 1)) & 3;
      async16(sA + c * 8, ag + row * 32 + qg * 8);
    }
#pragma unroll
    for (int c = t; c < B_CH; c += 256) {
      const int row = c >> 2, qs = c & 3, qg = (qs - (row >> 1)) & 3;
      async16(sB + c * 8, bg + row * 32 + qg * 8);
    }
    __syncthreads();
    v8bf af[MF], bfr[NF];
#pragma unroll
    for (int i = 0; i < MF; ++i) {
      const int row = wm + i * 16 + r16;
      af[i] = *(const v8bf*)(sA + row * 32 + (((q + (row >> 1)) & 3) * 8));
    }
#pragma unroll
    for (int j = 0; j < NF; ++j) {
      const int row = wn + j * 16 + r16;
      bfr[j] = *(const v8bf*)(sB + row * 32 + (((q + (row >> 1)) & 3) * 8));
    }
#pragma unroll
    for (int i = 0; i < MF; ++i)
#pragma unroll
      for (int j = 0; j < NF; ++j)
        acc[i][j] = __builtin_amdgcn_mfma_f32_16x16x32_bf16(af[i], bfr[j], acc[i][j], 0, 0, 0);
    __syncthreads();
  }

#pragma unroll
  for (int j = 0; j < NF; ++j) {
    const int gn = by * BN + wn + j * 16 + r16;
    const float bv = bias[gn];
#pragma unroll
    for (int i = 0; i < MF; ++i) {
      const int gm0 = M0 + bx * BM + wm + i * 16 + q * 4;
#pragma unroll
      for (int r = 0; r < 4; ++r) {
        float v = acc[i][j][r] + bv;
        if (relu_flag) v = fmaxf(v, 0.f);
        const int gm = gm0 + r;
        if (outF) outF[(size_t)gm * ldF + gn] = v;
        if (outP) {
          const int mt = gm >> bmsh, mm = gm & ((1 << bmsh) - 1);
          outP[(((size_t)mt * ktN + (gn >> 5)) << (bmsh + 5)) + ((size_t)mm << 5) + (gn & 31)] = (bf16)v;
        }
      }
    }
  }
}

template <int BM, int BN, int MF, int NF>
__global__ __launch_bounds__(256, 2) void gemm_kernel(
    const bf16* __restrict__ Ap, const bf16* __restrict__ Bp,
    const float* __restrict__ bias,
    float* __restrict__ outF, int ldF,
    bf16* __restrict__ outP, int ktN, int bmsh,
    int KT, int M0, int relu_flag) {
  __shared__ __align__(16) bf16 sA[BM * 32];
  __shared__ __align__(16) bf16 sB[BN * 32];
  gemm_body<BM, BN, MF, NF>(Ap, Bp, bias, outF, ldF, outP, ktN, bmsh,
                            KT, M0, relu_flag, blockIdx.x, blockIdx.y, sA, sB);
}

// two independent GEMMs (z=0,1) + optional embed slice (z=2)
template <int BM, int BN, int MF, int NF>
__global__ __launch_bounds__(256, 2) void gemm_dual_kernel(
    const bf16* Ap0, const bf16* Bp0, const float* bias0,
    float* outF0, int ldF0, bf16* outP0, int ktN0, int bmsh0, int KT0, int relu0, int gy0,
    const bf16* Ap1, const bf16* Bp1, const float* bias1,
    float* outF1, int ldF1, bf16* outP1, int ktN1, int bmsh1, int KT1, int relu1, int gy1,
    const int* xs, const float* emb, float* cf) {
  __shared__ __align__(16) bf16 sA[BM * 32];
  __shared__ __align__(16) bf16 sB[BN * 32];
  if (blockIdx.z == 0) {
    if ((int)blockIdx.y >= gy0) return;
    gemm_body<BM, BN, MF, NF>(Ap0, Bp0, bias0, outF0, ldF0, outP0, ktN0, bmsh0,
                              KT0, 0, relu0, blockIdx.x, blockIdx.y, sA, sB);
  } else if (blockIdx.z == 1) {
    if ((int)blockIdx.y >= gy1) return;
    gemm_body<BM, BN, MF, NF>(Ap1, Bp1, bias1, outF1, ldF1, outP1, ktN1, bmsh1,
                              KT1, 0, relu1, blockIdx.x, blockIdx.y, sA, sB);
  } else {
    embed8_dev(xs, emb, cf, blockIdx.y * 64 + blockIdx.x);
  }
}

// ---------------------------------------------------------------- MX fp8 split-K GEMM -> bf16 partials [S][Mchunk][1024]
__global__ __launch_bounds__(256, 3) void gemm_splitk_mx(
    const u8* __restrict__ Ap, const u8* __restrict__ Bp,
    bf16* __restrict__ part, int S, int Mchunk) {
  __shared__ __align__(16) u8 sA[2][8192];
  __shared__ __align__(16) u8 sB[2][8192];
  const int t = threadIdx.x;
  const int bx = blockIdx.x, by = blockIdx.y, bz = blockIdx.z;
  const int wid = t >> 6, lane = t & 63;
  const int wm = (wid >> 1) * 64, wn = (wid & 1) * 64;
  const int l31 = lane & 31, khalf = lane >> 5;
  const int kw0 = (291 * bz) / S, kw1 = (291 * (bz + 1)) / S;

  f32x16 acc[2][2];
#pragma unroll
  for (int i = 0; i < 2; ++i)
#pragma unroll
    for (int j = 0; j < 2; ++j)
#pragma unroll
      for (int r = 0; r < 16; ++r) acc[i][j][r] = 0.f;

  const u8* aBase = Ap + (size_t)bx * 291 * 8192;
  const u8* bBase = Bp + (size_t)by * 291 * 8192;

  auto stage = [&](int buf, int kw) {
    const u8* ag = aBase + (size_t)kw * 8192;
    const u8* bg = bBase + (size_t)kw * 8192;
#pragma unroll
    for (int c = t; c < 512; c += 256) {
      const int row = c >> 2, qs = c & 3, qg = (qs - (row >> 1)) & 3;
      async16(sA[buf] + c * 16, ag + row * 64 + qg * 16);
    }
#pragma unroll
    for (int c = t; c < 512; c += 256) {
      const int row = c >> 2, qs = c & 3, qg = (qs - (row >> 1)) & 3;
      async16(sB[buf] + c * 16, bg + row * 64 + qg * 16);
    }
  };
  auto frag = [&](const u8* s, int row) -> v8i32 {
    const int q0 = (khalf * 2 + (row >> 1)) & 3;
    const int q1 = (khalf * 2 + 1 + (row >> 1)) & 3;
    union { i32x4 h[2]; v8i32 v; } u;
    u.h[0] = *(const i32x4*)(s + row * 64 + q0 * 16);
    u.h[1] = *(const i32x4*)(s + row * 64 + q1 * 16);
    return u.v;
  };
  auto compute = [&](int buf) {
    v8i32 av[2], bv[2];
#pragma unroll
    for (int i = 0; i < 2; ++i) av[i] = frag(sA[buf], wm + i * 32 + l31);
#pragma unroll
    for (int j = 0; j < 2; ++j) bv[j] = frag(sB[buf], wn + j * 32 + l31);
#pragma unroll
    for (int i = 0; i < 2; ++i)
#pragma unroll
      for (int j = 0; j < 2; ++j)
        acc[i][j] = __builtin_amdgcn_mfma_scale_f32_32x32x64_f8f6f4(
            av[i], bv[j], acc[i][j], 0, 0,
            0, 0x7F7F7F7F,   // A scale: 2^0
            0, 0x7A7A7A7A);  // B scale: 2^-5
  };

  int kw = kw0;
  for (; kw + 1 < kw1; kw += 2) {
    stage(0, kw);
    stage(1, kw + 1);
    __syncthreads();
    compute(0);
    compute(1);
    __syncthreads();
  }
  if (kw < kw1) {
    stage(0, kw);
    __syncthreads();
    compute(0);
    __syncthreads();
  }

  bf16* pBase = part + (size_t)bz * Mchunk * 1024;
#pragma unroll
  for (int i = 0; i < 2; ++i)
#pragma unroll
    for (int j = 0; j < 2; ++j) {
      const int gn = by * 128 + wn + j * 32 + l31;
#pragma unroll
      for (int r = 0; r < 16; ++r) {
        const int gm = bx * 128 + wm + i * 32 + (r & 3) + 8 * (r >> 2) + 4 * khalf;
        pBase[(size_t)gm * 1024 + gn] = (bf16)acc[i][j][r];
      }
    }
}

// ---------------------------------------------------------------- split-K reduce -> t1 packed bf16 (BM=64)
__global__ __launch_bounds__(256) void reducek_kernel(const bf16* __restrict__ part,
                                                      const float* __restrict__ bias,
                                                      bf16* __restrict__ t1,
                                                      int S, int Mchunk, int M0) {
  const int idx = blockIdx.x * 256 + threadIdx.x;
  const int gm = idx >> 7;
  const int gn8 = (idx & 127) * 8;
  float v[8] = {0.f, 0.f, 0.f, 0.f, 0.f, 0.f, 0.f, 0.f};
  for (int s = 0; s < S; ++s) {
    v8bf p = *(const v8bf*)(part + ((size_t)s * Mchunk + gm) * 1024 + gn8);
#pragma unroll
    for (int r = 0; r < 8; ++r) v[r] += (float)p[r];
  }
  const f32x4 b0 = *(const f32x4*)(bias + gn8);
  const f32x4 b1 = *(const f32x4*)(bias + gn8 + 4);
  __align__(16) bf16 h[8];
#pragma unroll
  for (int r = 0; r < 4; ++r) h[r] = (bf16)fmaxf(v[r] + b0[r], 0.f);
#pragma unroll
  for (int r = 0; r < 4; ++r) h[4 + r] = (bf16)fmaxf(v[4 + r] + b1[r], 0.f);
  const int G = M0 + gm;
  const int mt = G >> 6, mm = G & 63, kt = gn8 >> 5;
  *(i32x4*)(t1 + (((size_t)mt * 32 + kt) << 11) + (mm << 5) + (gn8 & 31)) = *(const i32x4*)h;
}

// ---------------------------------------------------------------- batchnorm stats
__global__ __launch_bounds__(256) void bnstats_kernel(const float* __restrict__ z,
                                                      float* __restrict__ stats) {
  const int j = blockIdx.x, t = threadIdx.x;
  float s = 0.f, s2 = 0.f;
  for (int b = t; b < 4096; b += 256) {
    float v = z[(size_t)b * 64 + j];
    s += v; s2 += v * v;
  }
  __shared__ float sh[256], sh2[256];
  sh[t] = s; sh2[t] = s2;
  __syncthreads();
  for (int o = 128; o > 0; o >>= 1) {
    if (t < o) { sh[t] += sh[t + o]; sh2[t] += sh2[t + o]; }
    __syncthreads();
  }
  if (t == 0) {
    float mu = sh[0] * (1.f / 4096.f);
    float var = sh2[0] * (1.f / 4096.f) - mu * mu;
    stats[j] = mu;
    stats[64 + j] = rsqrtf(var + 1e-5f);
  }
}

// ---------------------------------------------------------------- normalize -> cf[:,64:128], d_out tail, cf[:,192]=1
__global__ __launch_bounds__(256) void cfbuild_kernel(const float* __restrict__ z,
                                                      const float* __restrict__ stats,
                                                      const float* __restrict__ gamma,
                                                      const float* __restrict__ beta,
                                                      float* __restrict__ cf,
                                                      float* __restrict__ dout) {
  const int wid = threadIdx.x >> 6, lane = threadIdx.x & 63;
  const int b = blockIdx.x * 4 + wid;
  const float mu = stats[lane], rstd = stats[64 + lane];
  const float xe = gamma[lane] * (z[(size_t)b * 64 + lane] - mu) * rstd + beta[lane];
  cf[(size_t)b * 193 + 64 + lane] = xe;
  dout[4096 + (size_t)b * 64 + lane] = xe;
  if (lane == 0) cf[(size_t)b * 193 + 192] = 1.f;
}

// ---------------------------------------------------------------- interaction A -> fp8 tiles [mt][kw 291][128][64]
__global__ __launch_bounds__(256, 2) void agen_kernel(const float* __restrict__ cf,
                                                      const u16* __restrict__ pairs,
                                                      u8* __restrict__ Ap, int rowBase) {
  __shared__ float sCF[64 * 193];
  const int t = threadIdx.x;
  const int gRow0 = rowBase + blockIdx.x * 64;
  for (int i = t; i < 64 * 193; i += 256) sCF[i] = cf[(size_t)gRow0 * 193 + i];
  __syncthreads();
  const int kw0 = (291 * blockIdx.y) / 8;
  const int kw1 = (291 * (blockIdx.y + 1)) / 8;
  const int row = t >> 2, kq = t & 3;
  const int mt = blockIdx.x >> 1;
  const int mrow = (blockIdx.x & 1) * 64 + row;
  const float* myrow = sCF + row * 193;
  for (int kw = kw0; kw < kw1; ++kw) {
    const int kb = kw * 64 + kq * 16;
    union { i32x4 v4[2]; u16 u[16]; } P;
    P.v4[0] = *(const i32x4*)(pairs + kb);
    P.v4[1] = *(const i32x4*)(pairs + kb + 8);
    i32x4 d;
#pragma unroll
    for (int g = 0; g < 4; ++g) {
      float p[4];
#pragma unroll
      for (int j = 0; j < 4; ++j) {
        const u16 pr = P.u[g * 4 + j];
        p[j] = myrow[pr >> 8] * myrow[pr & 255];
      }
      int r = __builtin_amdgcn_cvt_pk_fp8_f32(p[0], p[1], 0, false);
      r = __builtin_amdgcn_cvt_pk_fp8_f32(p[2], p[3], r, true);
      d[g] = r;
    }
    *(i32x4*)(Ap + (((size_t)mt * 291 + kw) * 128 + mrow) * 64 + kq * 16) = d;
  }
}

// ---------------------------------------------------------------- final dot (512->1) + sigmoid
__global__ __launch_bounds__(256) void topdot_kernel(const float* __restrict__ t2,
                                                     const float* __restrict__ w,
                                                     const float* __restrict__ b3,
                                                     float* __restrict__ dout) {
  const int wid = threadIdx.x >> 6, lane = threadIdx.x & 63;
  const int b = blockIdx.x * 4 + wid;
  const f32x4* row = (const f32x4*)(t2 + (size_t)b * 512);
  const f32x4* wv = (const f32x4*)w;
  float s = 0.f;
#pragma unroll
  for (int i = 0; i < 2; ++i) {
    f32x4 a = row[lane * 2 + i], c = wv[lane * 2 + i];
    s += a[0] * c[0] + a[1] * c[1] + a[2] * c[2] + a[3] * c[3];
  }
  for (int m = 32; m > 0; m >>= 1) s += __shfl_xor(s, m, 64);
  if (lane == 0) dout[b] = 1.f / (1.f + __expf(-(s + b3[0])));
}

// ================================================================ launch
extern "C" void kernel_launch(void* const* d_in, const int* in_sizes, int n_in,
                              void* d_out, int out_size, void* d_ws, size_t ws_size,
                              hipStream_t stream) {
  const int*   xs   = (const int*)  d_in[0];
  const float* xd   = (const float*)d_in[1];
  const float* xep  = (const float*)d_in[2];
  const float* emb  = (const float*)d_in[3];
  const float* pw1  = (const float*)d_in[4];
  const float* pb1  = (const float*)d_in[5];
  const float* pw2  = (const float*)d_in[6];
  const float* pb2  = (const float*)d_in[7];
  const float* gmma = (const float*)d_in[8];
  const float* beta = (const float*)d_in[9];
  const float* bw1  = (const float*)d_in[10];
  const float* bb1  = (const float*)d_in[11];
  const float* bw2  = (const float*)d_in[12];
  const float* bb2  = (const float*)d_in[13];
  const float* tw1  = (const float*)d_in[14];
  const float* tb1  = (const float*)d_in[15];
  const float* tw2  = (const float*)d_in[16];
  const float* tb2  = (const float*)d_in[17];
  const float* tw3  = (const float*)d_in[18];
  const float* tb3  = (const float*)d_in[19];
  float* out = (float*)d_out;

  uint8_t* base = (uint8_t*)d_ws;
  size_t off = 0;
  auto alloc = [&](size_t b) {
    void* p = base + off;
    off = (off + b + 511) & ~((size_t)511);
    return p;
  };
  u16*  pairs = (u16*) alloc((size_t)18624 * 2);
  bf16* Xp    = (bf16*)alloc((size_t)4096 * 768 * 2);
  bf16* Xd    = (bf16*)alloc((size_t)4096 * 256 * 2);
  bf16* Bpw1  = (bf16*)alloc((size_t)768 * 256 * 2);
  bf16* Bpw2  = (bf16*)alloc((size_t)256 * 64 * 2);
  bf16* Bbw1  = (bf16*)alloc((size_t)256 * 512 * 2);
  bf16* Bbw2  = (bf16*)alloc((size_t)512 * 64 * 2);
  u8*   Btw1  = (u8*)  alloc((size_t)8 * 291 * 8192);      // fp8 tiles
  bf16* Btw2  = (bf16*)alloc((size_t)1024 * 512 * 2);
  bf16* hbuf  = (bf16*)alloc((size_t)4096 * 256 * 2);
  float* z    = (float*)alloc((size_t)4096 * 64 * 4);
  float* stats= (float*)alloc((size_t)128 * 4);
  bf16* b0    = (bf16*)alloc((size_t)4096 * 512 * 2);
  float* cf   = (float*)alloc((size_t)4096 * 193 * 4);
  bf16* t1    = (bf16*)alloc((size_t)4096 * 1024 * 2);
  float* t2   = (float*)alloc((size_t)4096 * 512 * 4);
  size_t fixedEnd = off;

  // pick (chunk, S): Ap fp8 = chunk*18624 B; partK bf16 = S*chunk*1024*2 B
  int chunk = 512, S = 8;
  {
    const int candC[5] = {4096, 4096, 2048, 1024, 512};
    const int candS[5] = {8, 4, 8, 8, 8};
    for (int i = 0; i < 5; ++i) {
      size_t need = fixedEnd + (size_t)candC[i] * 18624 + 1024 +
                    (size_t)candS[i] * candC[i] * 1024 * 2 + 1024;
      if (need <= ws_size) { chunk = candC[i]; S = candS[i]; break; }
    }
  }
  u8*   ApBig = (u8*)  alloc((size_t)chunk * 18624);
  bf16* partK = (bf16*)alloc((size_t)S * chunk * 1024 * 2);

  // ---- fused prologue (packs + pairs) ----
  prologue_kernel<<<4817, 256, 0, stream>>>(
      xep, xd, pw1, pw2, bw1, bw2, tw1, tw2,
      Xp, Xd, Bpw1, Bpw2, Bbw1, Bbw2, Btw1, Btw2, pairs);

  // ---- dual1: proj1 || bot1 || embed (z=2) ----
  gemm_dual_kernel<64, 64, 2, 2><<<dim3(64, 8, 3), 256, 0, stream>>>(
      Xp, Bpw1, pb1, nullptr, 0, hbuf, 8, 6, 24, 1, 4,
      Xd, Bbw1, bb1, nullptr, 0, b0, 16, 6, 8, 1, 8,
      xs, emb, cf);
  // ---- dual2: proj2 (h@pw2 -> z f32) || bot2 (b0@bw2 -> cf[:,0:64]) ----
  gemm_dual_kernel<64, 64, 2, 2><<<dim3(64, 1, 2), 256, 0, stream>>>(
      hbuf, Bpw2, pb2, z, 64, nullptr, 0, 0, 8, 0, 1,
      b0, Bbw2, bb2, cf, 193, nullptr, 0, 0, 16, 1, 1,
      nullptr, nullptr, nullptr);

  bnstats_kernel<<<64, 256, 0, stream>>>(z, stats);
  cfbuild_kernel<<<1024, 256, 0, stream>>>(z, stats, gmma, beta, cf, out);

  // ---- interaction (fp8) + MX split-K GEMM + reduce ----
  for (int c0 = 0; c0 < 4096; c0 += chunk) {
    agen_kernel<<<dim3(chunk / 64, 8), 256, 0, stream>>>(cf, pairs, ApBig, c0);
    gemm_splitk_mx<<<dim3(chunk / 128, 8, S), 256, 0, stream>>>(
        ApBig, Btw1, partK, S, chunk);
    reducek_kernel<<<chunk / 2, 256, 0, stream>>>(partK, tb1, t1, S, chunk, c0);
  }

  // ---- top2: t2 = relu(t1@tw2+tb2) ----
  gemm_kernel<64, 64, 2, 2><<<dim3(64, 8), 256, 0, stream>>>(
      t1, Btw2, tb2, t2, 512, nullptr, 0, 0, 32, 0, 1);
  // ---- top3: sigmoid(t2@tw3+tb3) -> out[0:4096] ----
  topdot_kernel<<<1024, 256, 0, stream>>>(t2, tw3, tb3, out);
}

// Round 6
// 353.586 us; speedup vs baseline: 2.2192x; 1.0198x over previous
//
#include <hip/hip_runtime.h>
#include <hip/hip_bf16.h>
#include <cstdint>
#include <cstddef>

typedef __bf16 bf16;
typedef unsigned char u8;
typedef unsigned short u16;
typedef __bf16 v8bf  __attribute__((ext_vector_type(8)));
typedef float  f32x4 __attribute__((ext_vector_type(4)));
typedef float  f32x16 __attribute__((ext_vector_type(16)));
typedef int    i32x4 __attribute__((ext_vector_type(4)));
typedef int    v8i32 __attribute__((ext_vector_type(8)));

// ---------------------------------------------------------------- async copy
__device__ __forceinline__ void async16(void* lds, const void* g) {
  __builtin_amdgcn_global_load_lds(
      (const __attribute__((address_space(1))) unsigned int*)g,
      (__attribute__((address_space(3))) unsigned int*)lds, 16, 0, 0);
}

// LDS tiles XOR-swizzled at 16B quarter granularity (R2: bf16 conflicts ->0).
// Big GEMM: MX fp8 e4m3, K padded 18592->18624 = 291 windows of 64.
// B pre-scaled by 2^5 at pack; HW block scale 0x7A (=2^-5) undoes it.

// ================================================================ prologue device funcs
__device__ __forceinline__ void pairs_dev(u16* __restrict__ pairs) {
  int r = threadIdx.x;
  if (r < 192) {
    int off = 192 * r - (r * (r - 1)) / 2;
    for (int c = r; c < 192; ++c) pairs[off + c - r] = (u16)((r << 8) | c);
  } else if (r == 192) {
    for (int j = 0; j < 64; ++j) pairs[18528 + j] = (u16)((j << 8) | 192);
  } else if (r == 193) {
    for (int j = 18592; j < 18624; ++j) pairs[j] = (u16)((192 << 8) | 192);  // pad (B=0)
  }
}

// pack A (f32 row-major -> bf16 tiles [mt][kt][64][32])
__device__ __forceinline__ void packA_dev(const float* __restrict__ A,
                                          bf16* __restrict__ Ap, int K,
                                          int bx, int by) {
  const int t = threadIdx.x;
  const int KT = K >> 5;
  const size_t tile = ((size_t)bx * KT + by) * (64 * 32);
  const int c = t;
  const int mm = c >> 2, koct = (c & 3) * 8;
  const float* src = A + (size_t)(bx * 64 + mm) * K + by * 32 + koct;
  f32x4 f0 = *(const f32x4*)src;
  f32x4 f1 = *(const f32x4*)(src + 4);
  __align__(16) bf16 h[8];
  h[0]=(bf16)f0[0]; h[1]=(bf16)f0[1]; h[2]=(bf16)f0[2]; h[3]=(bf16)f0[3];
  h[4]=(bf16)f1[0]; h[5]=(bf16)f1[1]; h[6]=(bf16)f1[2]; h[7]=(bf16)f1[3];
  *(i32x4*)(Ap + tile + (size_t)c * 8) = *(const i32x4*)h;
}

// pack B (f32 [K][N] -> bf16 tiles [nt][kt][64][32])
__device__ __forceinline__ void packB_dev(const float* __restrict__ B,
                                          bf16* __restrict__ Bp, int K, int N,
                                          int bx, int by,
                                          float* __restrict__ sLB) {
  const int BNp = 64, LS = 66;
  const int t = threadIdx.x;
  const int KT = K >> 5;
  for (int idx = t; idx < 32 * BNp; idx += 256) {
    const int kk = idx >> 6, nn = idx & 63;
    sLB[kk * LS + nn] = B[(size_t)(by * 32 + kk) * N + bx * BNp + nn];
  }
  __syncthreads();
  const size_t tile = ((size_t)bx * KT + by) * ((size_t)BNp * 32);
  for (int c = t; c < BNp * 4; c += 256) {
    const int nn = c >> 2, koct = (c & 3) * 8;
    __align__(16) bf16 h[8];
#pragma unroll
    for (int j = 0; j < 8; ++j) h[j] = (bf16)sLB[(koct + j) * LS + nn];
    *(i32x4*)(Bp + tile + (size_t)c * 8) = *(const i32x4*)h;
  }
}

// pack tw1 -> fp8 e4m3 tiles [nt 8][kw 291][n 128][k 64 bytes], values *32.
__device__ __forceinline__ void packTw1_dev(const float* __restrict__ tw1,
                                            u8* __restrict__ Bp, int nt, int kw,
                                            float* __restrict__ sLB) {
  const int t = threadIdx.x;
  u8* tile = Bp + ((size_t)nt * 291 + kw) * 8192;
#pragma unroll
  for (int ph = 0; ph < 2; ++ph) {
    if (ph) __syncthreads();
#pragma unroll
    for (int idx = t; idx < 1024; idx += 256) {
      const int kk = idx >> 5, nn4 = (idx & 31) * 4;
      const int gk = kw * 64 + ph * 32 + kk;
      f32x4 v = f32x4{0.f, 0.f, 0.f, 0.f};
      if (gk < 18592) {
        v = *(const f32x4*)(tw1 + (size_t)gk * 1024 + nt * 128 + nn4);
        v *= 32.f;
      }
      *(f32x4*)(sLB + kk * 132 + nn4) = v;
    }
    __syncthreads();
    const int nn = t >> 1;
    const int hkb = (t & 1) * 16;
    const int c = nn * 4 + ph * 2 + (t & 1);
    i32x4 d;
#pragma unroll
    for (int g = 0; g < 4; ++g) {
      const float p0 = sLB[(hkb + g * 4 + 0) * 132 + nn];
      const float p1 = sLB[(hkb + g * 4 + 1) * 132 + nn];
      const float p2 = sLB[(hkb + g * 4 + 2) * 132 + nn];
      const float p3 = sLB[(hkb + g * 4 + 3) * 132 + nn];
      int r = __builtin_amdgcn_cvt_pk_fp8_f32(p0, p1, 0, false);
      r = __builtin_amdgcn_cvt_pk_fp8_f32(p2, p3, r, true);
      d[g] = r;
    }
    *(i32x4*)(tile + c * 16) = d;
  }
}

// ---------------------------------------------------------------- fused prologue
__global__ __launch_bounds__(256) void prologue_kernel(
    const float* __restrict__ xep, const float* __restrict__ xd,
    const float* __restrict__ pw1, const float* __restrict__ pw2,
    const float* __restrict__ bw1, const float* __restrict__ bw2,
    const float* __restrict__ tw1, const float* __restrict__ tw2,
    bf16* Xp, bf16* Xd, bf16* Bpw1, bf16* Bpw2, bf16* Bbw1, bf16* Bbw2,
    u8* Btw1, bf16* Btw2, u16* pairs) {
  __shared__ float sLB[32 * 132];
  int i = blockIdx.x;
  if (i < 2328) { packTw1_dev(tw1, Btw1, i & 7, i >> 3, sLB); return; }
  i -= 2328;
  if (i < 1536) { packA_dev(xep, Xp, 768, i & 63, i >> 6); return; }
  i -= 1536;
  if (i < 512)  { packA_dev(xd, Xd, 256, i & 63, i >> 6); return; }
  i -= 512;
  if (i < 96)   { packB_dev(pw1, Bpw1, 768, 256, i & 3, i >> 2, sLB); return; }
  i -= 96;
  if (i < 8)    { packB_dev(pw2, Bpw2, 256, 64, 0, i, sLB); return; }
  i -= 8;
  if (i < 64)   { packB_dev(bw1, Bbw1, 256, 512, i & 7, i >> 3, sLB); return; }
  i -= 64;
  if (i < 16)   { packB_dev(bw2, Bbw2, 512, 64, 0, i, sLB); return; }
  i -= 16;
  if (i < 256)  { packB_dev(tw2, Btw2, 1024, 512, i & 7, i >> 3, sLB); return; }
  i -= 256;
  if (i == 0) pairs_dev(pairs);
}

// embedding gather-sum -> cf[:,128:192], 8 rows per block
__device__ __forceinline__ void embed8_dev(const int* __restrict__ xs,
                                           const float* __restrict__ emb,
                                           float* __restrict__ cf, int blk) {
  const int wid = threadIdx.x >> 6, lane = threadIdx.x & 63;
#pragma unroll
  for (int s = 0; s < 2; ++s) {
    const int b = blk * 8 + s * 4 + wid;
    const int* row = xs + (size_t)b * 50;
    float acc = 0.f;
#pragma unroll 10
    for (int h = 0; h < 50; ++h) {
      int idx = row[h];
      acc += emb[(size_t)idx * 64 + lane];
    }
    cf[(size_t)b * 193 + 128 + lane] = acc;
  }
}

// ================================================================ bf16 MFMA GEMM body (small GEMMs)
template <int BM, int BN, int MF, int NF>
__device__ __forceinline__ void gemm_body(
    const bf16* __restrict__ Ap, const bf16* __restrict__ Bp,
    const float* __restrict__ bias,
    float* __restrict__ outF, int ldF,
    bf16* __restrict__ outP, int ktN, int bmsh,
    int KT, int M0, int relu_flag, int bx, int by,
    bf16* sA, bf16* sB) {
  const int t = threadIdx.x;
  const int wid = t >> 6, lane = t & 63;
  const int wm = (wid >> 1) * (MF * 16);
  const int wn = (wid & 1) * (NF * 16);
  const int r16 = lane & 15, q = lane >> 4;

  f32x4 acc[MF][NF];
#pragma unroll
  for (int i = 0; i < MF; ++i)
#pragma unroll
    for (int j = 0; j < NF; ++j) acc[i][j] = f32x4{0.f, 0.f, 0.f, 0.f};

  const bf16* aBase = Ap + (size_t)bx * KT * (BM * 32);
  const bf16* bBase = Bp + (size_t)by * KT * (BN * 32);
  constexpr int A_CH = BM * 4;
  constexpr int B_CH = BN * 4;

  for (int kt = 0; kt < KT; ++kt) {
    const bf16* ag = aBase + (size_t)kt * (BM * 32);
    const bf16* bg = bBase + (size_t)kt * (BN * 32);
#pragma unroll
    for (int c = t; c < A_CH; c += 256) {
      const int row = c >> 2, qs = c & 3, qg = (qs - (row >> 1)) & 3;
      async16(sA + c * 8, ag + row * 32 + qg * 8);
    }
#pragma unroll
    for (int c = t; c < B_CH; c += 256) {
      const int row = c >> 2, qs = c & 3, qg = (qs - (row >> 1)) & 3;
      async16(sB + c * 8, bg + row * 32 + qg * 8);
    }
    __syncthreads();
    v8bf af[MF], bfr[NF];
#pragma unroll
    for (int i = 0; i < MF; ++i) {
      const int row = wm + i * 16 + r16;
      af[i] = *(const v8bf*)(sA + row * 32 + (((q + (row >> 1)) & 3) * 8));
    }
#pragma unroll
    for (int j = 0; j < NF; ++j) {
      const int row = wn + j * 16 + r16;
      bfr[j] = *(const v8bf*)(sB + row * 32 + (((q + (row >> 1)) & 3) * 8));
    }
#pragma unroll
    for (int i = 0; i < MF; ++i)
#pragma unroll
      for (int j = 0; j < NF; ++j)
        acc[i][j] = __builtin_amdgcn_mfma_f32_16x16x32_bf16(af[i], bfr[j], acc[i][j], 0, 0, 0);
    __syncthreads();
  }

#pragma unroll
  for (int j = 0; j < NF; ++j) {
    const int gn = by * BN + wn + j * 16 + r16;
    const float bv = bias[gn];
#pragma unroll
    for (int i = 0; i < MF; ++i) {
      const int gm0 = M0 + bx * BM + wm + i * 16 + q * 4;
#pragma unroll
      for (int r = 0; r < 4; ++r) {
        float v = acc[i][j][r] + bv;
        if (relu_flag) v = fmaxf(v, 0.f);
        const int gm = gm0 + r;
        if (outF) outF[(size_t)gm * ldF + gn] = v;
        if (outP) {
          const int mt = gm >> bmsh, mm = gm & ((1 << bmsh) - 1);
          outP[(((size_t)mt * ktN + (gn >> 5)) << (bmsh + 5)) + ((size_t)mm << 5) + (gn & 31)] = (bf16)v;
        }
      }
    }
  }
}

template <int BM, int BN, int MF, int NF>
__global__ __launch_bounds__(256, 2) void gemm_kernel(
    const bf16* __restrict__ Ap, const bf16* __restrict__ Bp,
    const float* __restrict__ bias,
    float* __restrict__ outF, int ldF,
    bf16* __restrict__ outP, int ktN, int bmsh,
    int KT, int M0, int relu_flag) {
  __shared__ __align__(16) bf16 sA[BM * 32];
  __shared__ __align__(16) bf16 sB[BN * 32];
  gemm_body<BM, BN, MF, NF>(Ap, Bp, bias, outF, ldF, outP, ktN, bmsh,
                            KT, M0, relu_flag, blockIdx.x, blockIdx.y, sA, sB);
}

// two independent GEMMs (z=0,1) + optional embed slice (z=2)
template <int BM, int BN, int MF, int NF>
__global__ __launch_bounds__(256, 2) void gemm_dual_kernel(
    const bf16* Ap0, const bf16* Bp0, const float* bias0,
    float* outF0, int ldF0, bf16* outP0, int ktN0, int bmsh0, int KT0, int relu0, int gy0,
    const bf16* Ap1, const bf16* Bp1, const float* bias1,
    float* outF1, int ldF1, bf16* outP1, int ktN1, int bmsh1, int KT1, int relu1, int gy1,
    const int* xs, const float* emb, float* cf) {
  __shared__ __align__(16) bf16 sA[BM * 32];
  __shared__ __align__(16) bf16 sB[BN * 32];
  if (blockIdx.z == 0) {
    if ((int)blockIdx.y >= gy0) return;
    gemm_body<BM, BN, MF, NF>(Ap0, Bp0, bias0, outF0, ldF0, outP0, ktN0, bmsh0,
                              KT0, 0, relu0, blockIdx.x, blockIdx.y, sA, sB);
  } else if (blockIdx.z == 1) {
    if ((int)blockIdx.y >= gy1) return;
    gemm_body<BM, BN, MF, NF>(Ap1, Bp1, bias1, outF1, ldF1, outP1, ktN1, bmsh1,
                              KT1, 0, relu1, blockIdx.x, blockIdx.y, sA, sB);
  } else {
    embed8_dev(xs, emb, cf, blockIdx.y * 64 + blockIdx.x);
  }
}

// ---------------------------------------------------------------- MX fp8 split-K GEMM -> bf16 partials [S][Mchunk][1024]
// Register-tightened: all staging/fragment offsets hoisted; target <=64 arch VGPR
// (+64 AGPR acc = 128 total -> 4 waves/SIMD per m69 allocation quanta).
template <int S>
__global__ __launch_bounds__(256, 4) void gemm_splitk_mx(
    const u8* __restrict__ Ap, const u8* __restrict__ Bp,
    bf16* __restrict__ part, int Mchunk) {
  __shared__ __align__(16) u8 sAB[4][8192];   // [0..1]=A dbuf, [2..3]=B dbuf
  const int t = threadIdx.x;
  const int bx = blockIdx.x, by = blockIdx.y, bz = blockIdx.z;
  const int lane = t & 63, wid = t >> 6;
  const int wm = (wid >> 1) * 64, wn = (wid & 1) * 64;
  const int l31 = lane & 31, khalf = lane >> 5;
  const int kw0 = (291 * bz) / S, kw1 = (291 * (bz + 1)) / S;

  // invariant staging offsets: chunks c1=t, c2=t+256 (swizzled source)
  const int r1 = t >> 2;
  const int g1 = r1 * 64 + ((((t & 3) - (r1 >> 1)) & 3) << 4);
  const int r2 = (t + 256) >> 2;
  const int g2 = r2 * 64 + (((((t + 256) & 3) - (r2 >> 1)) & 3) << 4);
  u8* lA = &sAB[0][0] + t * 16;      // +4096 = second half, +8192 = buf1
  u8* lB = &sAB[2][0] + t * 16;

  // invariant fragment pointers (buf0); +off for buf1
  const u8* fa0[2]; const u8* fa1[2]; const u8* fb0[2]; const u8* fb1[2];
#pragma unroll
  for (int i = 0; i < 2; ++i) {
    const int ra = wm + i * 32 + l31;
    const int qa = (khalf * 2 + (ra >> 1)) & 3;
    fa0[i] = &sAB[0][0] + ra * 64 + qa * 16;
    fa1[i] = &sAB[0][0] + ra * 64 + (((qa + 1) & 3) << 4);
    const int rb = wn + i * 32 + l31;
    const int qb = (khalf * 2 + (rb >> 1)) & 3;
    fb0[i] = &sAB[2][0] + rb * 64 + qb * 16;
    fb1[i] = &sAB[2][0] + rb * 64 + (((qb + 1) & 3) << 4);
  }

  f32x16 acc[2][2];
#pragma unroll
  for (int i = 0; i < 2; ++i)
#pragma unroll
    for (int j = 0; j < 2; ++j)
#pragma unroll
      for (int r = 0; r < 16; ++r) acc[i][j][r] = 0.f;

  const u8* agp = Ap + ((size_t)bx * 291 + kw0) * 8192;
  const u8* bgp = Bp + ((size_t)by * 291 + kw0) * 8192;

  auto compute = [&](int off) {
    v8i32 av[2], bv[2];
#pragma unroll
    for (int i = 0; i < 2; ++i) {
      union { i32x4 h[2]; v8i32 v; } ua;
      ua.h[0] = *(const i32x4*)(fa0[i] + off);
      ua.h[1] = *(const i32x4*)(fa1[i] + off);
      av[i] = ua.v;
      union { i32x4 h[2]; v8i32 v; } ub;
      ub.h[0] = *(const i32x4*)(fb0[i] + off);
      ub.h[1] = *(const i32x4*)(fb1[i] + off);
      bv[i] = ub.v;
    }
#pragma unroll
    for (int i = 0; i < 2; ++i)
#pragma unroll
      for (int j = 0; j < 2; ++j)
        acc[i][j] = __builtin_amdgcn_mfma_scale_f32_32x32x64_f8f6f4(
            av[i], bv[j], acc[i][j], 0, 0,
            0, 0x7F7F7F7F,   // A scale 2^0
            0, 0x7A7A7A7A);  // B scale 2^-5
  };

  const int nw = kw1 - kw0;
  int w = 0;
  for (; w + 2 <= nw; w += 2) {
    async16(lA, agp + g1);         async16(lA + 4096, agp + g2);
    async16(lB, bgp + g1);         async16(lB + 4096, bgp + g2);
    async16(lA + 8192, agp + 8192 + g1); async16(lA + 12288, agp + 8192 + g2);
    async16(lB + 8192, bgp + 8192 + g1); async16(lB + 12288, bgp + 8192 + g2);
    agp += 16384; bgp += 16384;
    __syncthreads();
    compute(0);
    compute(8192);
    __syncthreads();
  }
  if (w < nw) {
    async16(lA, agp + g1); async16(lA + 4096, agp + g2);
    async16(lB, bgp + g1); async16(lB + 4096, bgp + g2);
    __syncthreads();
    compute(0);
    __syncthreads();
  }

  bf16* pBase = part + (size_t)bz * Mchunk * 1024;
#pragma unroll
  for (int i = 0; i < 2; ++i)
#pragma unroll
    for (int j = 0; j < 2; ++j) {
      const int gn = by * 128 + wn + j * 32 + l31;
#pragma unroll
      for (int r = 0; r < 16; ++r) {
        const int gm = bx * 128 + wm + i * 32 + (r & 3) + 8 * (r >> 2) + 4 * khalf;
        pBase[(size_t)gm * 1024 + gn] = (bf16)acc[i][j][r];
      }
    }
}

// ---------------------------------------------------------------- split-K reduce -> t1 packed bf16 (BM=64)
__global__ __launch_bounds__(256) void reducek_kernel(const bf16* __restrict__ part,
                                                      const float* __restrict__ bias,
                                                      bf16* __restrict__ t1,
                                                      int S, int Mchunk, int M0) {
  const int idx = blockIdx.x * 256 + threadIdx.x;
  const int gm = idx >> 7;
  const int gn8 = (idx & 127) * 8;
  float v[8] = {0.f, 0.f, 0.f, 0.f, 0.f, 0.f, 0.f, 0.f};
  for (int s = 0; s < S; ++s) {
    v8bf p = *(const v8bf*)(part + ((size_t)s * Mchunk + gm) * 1024 + gn8);
#pragma unroll
    for (int r = 0; r < 8; ++r) v[r] += (float)p[r];
  }
  const f32x4 b0 = *(const f32x4*)(bias + gn8);
  const f32x4 b1 = *(const f32x4*)(bias + gn8 + 4);
  __align__(16) bf16 h[8];
#pragma unroll
  for (int r = 0; r < 4; ++r) h[r] = (bf16)fmaxf(v[r] + b0[r], 0.f);
#pragma unroll
  for (int r = 0; r < 4; ++r) h[4 + r] = (bf16)fmaxf(v[4 + r] + b1[r], 0.f);
  const int G = M0 + gm;
  const int mt = G >> 6, mm = G & 63, kt = gn8 >> 5;
  *(i32x4*)(t1 + (((size_t)mt * 32 + kt) << 11) + (mm << 5) + (gn8 & 31)) = *(const i32x4*)h;
}

// ---------------------------------------------------------------- batchnorm stats (mu, rstd)
__global__ __launch_bounds__(256) void bnstats_kernel(const float* __restrict__ z,
                                                      float* __restrict__ stats) {
  const int j = blockIdx.x, t = threadIdx.x;
  float s = 0.f, s2 = 0.f;
  for (int b = t; b < 4096; b += 256) {
    float v = z[(size_t)b * 64 + j];
    s += v; s2 += v * v;
  }
  __shared__ float sh[256], sh2[256];
  sh[t] = s; sh2[t] = s2;
  __syncthreads();
  for (int o = 128; o > 0; o >>= 1) {
    if (t < o) { sh[t] += sh[t + o]; sh2[t] += sh2[t + o]; }
    __syncthreads();
  }
  if (t == 0) {
    float mu = sh[0] * (1.f / 4096.f);
    float var = sh2[0] * (1.f / 4096.f) - mu * mu;
    stats[j] = mu;
    stats[64 + j] = rsqrtf(var + 1e-5f);
  }
}

// ---------------------------------------------------------------- interaction A -> fp8 tiles [mt][kw 291][128][64]
// Fused BN normalize: builds cols 64:128 from raw z + stats inline; writes the
// x_embed output slice (by==0 only); col 192 = 1.
__global__ __launch_bounds__(256, 2) void agen_kernel(const float* __restrict__ cf,
                                                      const float* __restrict__ z,
                                                      const float* __restrict__ stats,
                                                      const float* __restrict__ gamma,
                                                      const float* __restrict__ beta,
                                                      const u16* __restrict__ pairs,
                                                      u8* __restrict__ Ap,
                                                      float* __restrict__ dout,
                                                      int rowBase) {
  __shared__ float sCF[64 * 193];
  const int t = threadIdx.x;
  const int gRow0 = rowBase + blockIdx.x * 64;
  // bottom cols 0:64
  for (int idx = t; idx < 64 * 64; idx += 256) {
    const int r = idx >> 6, c = idx & 63;
    sCF[r * 193 + c] = cf[(size_t)(gRow0 + r) * 193 + c];
  }
  // embed cols 128:192
  for (int idx = t; idx < 64 * 64; idx += 256) {
    const int r = idx >> 6, c = idx & 63;
    sCF[r * 193 + 128 + c] = cf[(size_t)(gRow0 + r) * 193 + 128 + c];
  }
  // normalize z -> cols 64:128 (+ dout tail once)
  for (int idx = t; idx < 64 * 64; idx += 256) {
    const int r = idx >> 6, c = idx & 63;
    const float xe = gamma[c] * (z[(size_t)(gRow0 + r) * 64 + c] - stats[c]) * stats[64 + c] + beta[c];
    sCF[r * 193 + 64 + c] = xe;
    if (blockIdx.y == 0) dout[4096 + (size_t)(gRow0 + r) * 64 + c] = xe;
  }
  if (t < 64) sCF[t * 193 + 192] = 1.f;
  __syncthreads();

  const int kw0 = (291 * blockIdx.y) / 8;
  const int kw1 = (291 * (blockIdx.y + 1)) / 8;
  const int row = t >> 2, kq = t & 3;
  const int mt = blockIdx.x >> 1;
  const int mrow = (blockIdx.x & 1) * 64 + row;
  const float* myrow = sCF + row * 193;
  for (int kw = kw0; kw < kw1; ++kw) {
    const int kb = kw * 64 + kq * 16;
    i32x4 d;
    if (kb >= 18592) {
      d = i32x4{0, 0, 0, 0};
    } else {
      union { i32x4 v4[2]; u16 u[16]; } P;
      P.v4[0] = *(const i32x4*)(pairs + kb);
      P.v4[1] = *(const i32x4*)(pairs + kb + 8);
#pragma unroll
      for (int g = 0; g < 4; ++g) {
        float p[4];
#pragma unroll
        for (int j = 0; j < 4; ++j) {
          const u16 pr = P.u[g * 4 + j];
          p[j] = myrow[pr >> 8] * myrow[pr & 255];
        }
        int r = __builtin_amdgcn_cvt_pk_fp8_f32(p[0], p[1], 0, false);
        r = __builtin_amdgcn_cvt_pk_fp8_f32(p[2], p[3], r, true);
        d[g] = r;
      }
    }
    *(i32x4*)(Ap + (((size_t)mt * 291 + kw) * 128 + mrow) * 64 + kq * 16) = d;
  }
}

// ---------------------------------------------------------------- final dot (512->1) + sigmoid
__global__ __launch_bounds__(256) void topdot_kernel(const float* __restrict__ t2,
                                                     const float* __restrict__ w,
                                                     const float* __restrict__ b3,
                                                     float* __restrict__ dout) {
  const int wid = threadIdx.x >> 6, lane = threadIdx.x & 63;
  const int b = blockIdx.x * 4 + wid;
  const f32x4* row = (const f32x4*)(t2 + (size_t)b * 512);
  const f32x4* wv = (const f32x4*)w;
  float s = 0.f;
#pragma unroll
  for (int i = 0; i < 2; ++i) {
    f32x4 a = row[lane * 2 + i], c = wv[lane * 2 + i];
    s += a[0] * c[0] + a[1] * c[1] + a[2] * c[2] + a[3] * c[3];
  }
  for (int m = 32; m > 0; m >>= 1) s += __shfl_xor(s, m, 64);
  if (lane == 0) dout[b] = 1.f / (1.f + __expf(-(s + b3[0])));
}

// ================================================================ launch
extern "C" void kernel_launch(void* const* d_in, const int* in_sizes, int n_in,
                              void* d_out, int out_size, void* d_ws, size_t ws_size,
                              hipStream_t stream) {
  const int*   xs   = (const int*)  d_in[0];
  const float* xd   = (const float*)d_in[1];
  const float* xep  = (const float*)d_in[2];
  const float* emb  = (const float*)d_in[3];
  const float* pw1  = (const float*)d_in[4];
  const float* pb1  = (const float*)d_in[5];
  const float* pw2  = (const float*)d_in[6];
  const float* pb2  = (const float*)d_in[7];
  const float* gmma = (const float*)d_in[8];
  const float* beta = (const float*)d_in[9];
  const float* bw1  = (const float*)d_in[10];
  const float* bb1  = (const float*)d_in[11];
  const float* bw2  = (const float*)d_in[12];
  const float* bb2  = (const float*)d_in[13];
  const float* tw1  = (const float*)d_in[14];
  const float* tb1  = (const float*)d_in[15];
  const float* tw2  = (const float*)d_in[16];
  const float* tb2  = (const float*)d_in[17];
  const float* tw3  = (const float*)d_in[18];
  const float* tb3  = (const float*)d_in[19];
  float* out = (float*)d_out;

  uint8_t* base = (uint8_t*)d_ws;
  size_t off = 0;
  auto alloc = [&](size_t b) {
    void* p = base + off;
    off = (off + b + 511) & ~((size_t)511);
    return p;
  };
  u16*  pairs = (u16*) alloc((size_t)18624 * 2);
  bf16* Xp    = (bf16*)alloc((size_t)4096 * 768 * 2);
  bf16* Xd    = (bf16*)alloc((size_t)4096 * 256 * 2);
  bf16* Bpw1  = (bf16*)alloc((size_t)768 * 256 * 2);
  bf16* Bpw2  = (bf16*)alloc((size_t)256 * 64 * 2);
  bf16* Bbw1  = (bf16*)alloc((size_t)256 * 512 * 2);
  bf16* Bbw2  = (bf16*)alloc((size_t)512 * 64 * 2);
  u8*   Btw1  = (u8*)  alloc((size_t)8 * 291 * 8192);
  bf16* Btw2  = (bf16*)alloc((size_t)1024 * 512 * 2);
  bf16* hbuf  = (bf16*)alloc((size_t)4096 * 256 * 2);
  float* z    = (float*)alloc((size_t)4096 * 64 * 4);
  float* stats= (float*)alloc((size_t)128 * 4);
  bf16* b0    = (bf16*)alloc((size_t)4096 * 512 * 2);
  float* cf   = (float*)alloc((size_t)4096 * 193 * 4);
  bf16* t1    = (bf16*)alloc((size_t)4096 * 1024 * 2);
  float* t2   = (float*)alloc((size_t)4096 * 512 * 4);
  size_t fixedEnd = off;

  // pick (chunk, S): Ap fp8 = chunk*18624 B; partK bf16 = S*chunk*1024*2 B
  int chunk = 512, S = 8;
  {
    const int candC[5] = {4096, 2048, 2048, 1024, 512};
    const int candS[5] = {4, 8, 4, 8, 8};
    for (int i = 0; i < 5; ++i) {
      size_t need = fixedEnd + (size_t)candC[i] * 18624 + 1024 +
                    (size_t)candS[i] * candC[i] * 1024 * 2 + 1024;
      if (need <= ws_size) { chunk = candC[i]; S = candS[i]; break; }
    }
  }
  u8*   ApBig = (u8*)  alloc((size_t)chunk * 18624);
  bf16* partK = (bf16*)alloc((size_t)S * chunk * 1024 * 2);

  // ---- fused prologue (packs + pairs) ----
  prologue_kernel<<<4817, 256, 0, stream>>>(
      xep, xd, pw1, pw2, bw1, bw2, tw1, tw2,
      Xp, Xd, Bpw1, Bpw2, Bbw1, Bbw2, Btw1, Btw2, pairs);

  // ---- dual1: proj1 || bot1 || embed (z=2) ----
  gemm_dual_kernel<64, 64, 2, 2><<<dim3(64, 8, 3), 256, 0, stream>>>(
      Xp, Bpw1, pb1, nullptr, 0, hbuf, 8, 6, 24, 1, 4,
      Xd, Bbw1, bb1, nullptr, 0, b0, 16, 6, 8, 1, 8,
      xs, emb, cf);
  // ---- dual2: proj2 (h@pw2 -> z f32) || bot2 (b0@bw2 -> cf[:,0:64]) ----
  gemm_dual_kernel<64, 64, 2, 2><<<dim3(64, 1, 2), 256, 0, stream>>>(
      hbuf, Bpw2, pb2, z, 64, nullptr, 0, 0, 8, 0, 1,
      b0, Bbw2, bb2, cf, 193, nullptr, 0, 0, 16, 1, 1,
      nullptr, nullptr, nullptr);

  bnstats_kernel<<<64, 256, 0, stream>>>(z, stats);

  // ---- interaction (fp8, BN fused) + MX split-K GEMM + reduce ----
  for (int c0 = 0; c0 < 4096; c0 += chunk) {
    agen_kernel<<<dim3(chunk / 64, 8), 256, 0, stream>>>(
        cf, z, stats, gmma, beta, pairs, ApBig, out, c0);
    if (S == 4)
      gemm_splitk_mx<4><<<dim3(chunk / 128, 8, 4), 256, 0, stream>>>(
          ApBig, Btw1, partK, chunk);
    else
      gemm_splitk_mx<8><<<dim3(chunk / 128, 8, 8), 256, 0, stream>>>(
          ApBig, Btw1, partK, chunk);
    reducek_kernel<<<chunk / 2, 256, 0, stream>>>(partK, tb1, t1, S, chunk, c0);
  }

  // ---- top2: t2 = relu(t1@tw2+tb2) ----
  gemm_kernel<64, 64, 2, 2><<<dim3(64, 8), 256, 0, stream>>>(
      t1, Btw2, tb2, t2, 512, nullptr, 0, 0, 32, 0, 1);
  // ---- top3: sigmoid(t2@tw3+tb3) -> out[0:4096] ----
  topdot_kernel<<<1024, 256, 0, stream>>>(t2, tw3, tb3, out);
}

// Round 7
// 341.867 us; speedup vs baseline: 2.2953x; 1.0343x over previous
//
#include <hip/hip_runtime.h>
#include <hip/hip_bf16.h>
#include <cstdint>
#include <cstddef>

typedef __bf16 bf16;
typedef unsigned char u8;
typedef unsigned short u16;
typedef __bf16 v8bf  __attribute__((ext_vector_type(8)));
typedef float  f32x4 __attribute__((ext_vector_type(4)));
typedef float  f32x16 __attribute__((ext_vector_type(16)));
typedef int    i32x4 __attribute__((ext_vector_type(4)));
typedef int    i32x2 __attribute__((ext_vector_type(2)));
typedef int    v8i32 __attribute__((ext_vector_type(8)));

// ---------------------------------------------------------------- async copy
__device__ __forceinline__ void async16(void* lds, const void* g) {
  __builtin_amdgcn_global_load_lds(
      (const __attribute__((address_space(1))) unsigned int*)g,
      (__attribute__((address_space(3))) unsigned int*)lds, 16, 0, 0);
}

// LDS tiles XOR-swizzled at 16B quarter granularity (R2: verified 0 conflicts bf16).
// Big GEMM: MX fp8 e4m3, K padded 18592->18624 = 291 windows of 64.
// B pre-scaled by 2^5 at pack; HW block scale 0x7A (=2^-5) undoes it.

// ================================================================ prologue device funcs
__device__ __forceinline__ void pairs_dev(u16* __restrict__ pairs, float* __restrict__ stats) {
  int r = threadIdx.x;
  if (r < 128) stats[r] = 0.f;   // zero BN accumulators (sum, sumsq)
  if (r < 192) {
    int off = 192 * r - (r * (r - 1)) / 2;
    for (int c = r; c < 192; ++c) pairs[off + c - r] = (u16)((r << 8) | c);
  } else if (r == 192) {
    for (int j = 0; j < 64; ++j) pairs[18528 + j] = (u16)((j << 8) | 192);
  } else if (r == 193) {
    for (int j = 18592; j < 18624; ++j) pairs[j] = (u16)((192 << 8) | 192);  // pad (B=0)
  }
}

// pack A (f32 row-major -> bf16 tiles [mt][kt][64][32])
__device__ __forceinline__ void packA_dev(const float* __restrict__ A,
                                          bf16* __restrict__ Ap, int K,
                                          int bx, int by) {
  const int t = threadIdx.x;
  const int KT = K >> 5;
  const size_t tile = ((size_t)bx * KT + by) * (64 * 32);
  const int c = t;
  const int mm = c >> 2, koct = (c & 3) * 8;
  const float* src = A + (size_t)(bx * 64 + mm) * K + by * 32 + koct;
  f32x4 f0 = *(const f32x4*)src;
  f32x4 f1 = *(const f32x4*)(src + 4);
  __align__(16) bf16 h[8];
  h[0]=(bf16)f0[0]; h[1]=(bf16)f0[1]; h[2]=(bf16)f0[2]; h[3]=(bf16)f0[3];
  h[4]=(bf16)f1[0]; h[5]=(bf16)f1[1]; h[6]=(bf16)f1[2]; h[7]=(bf16)f1[3];
  *(i32x4*)(Ap + tile + (size_t)c * 8) = *(const i32x4*)h;
}

// pack B (f32 [K][N] -> bf16 tiles [nt][kt][64][32])
__device__ __forceinline__ void packB_dev(const float* __restrict__ B,
                                          bf16* __restrict__ Bp, int K, int N,
                                          int bx, int by,
                                          float* __restrict__ sLB) {
  const int BNp = 64, LS = 66;
  const int t = threadIdx.x;
  const int KT = K >> 5;
  for (int idx = t; idx < 32 * BNp; idx += 256) {
    const int kk = idx >> 6, nn = idx & 63;
    sLB[kk * LS + nn] = B[(size_t)(by * 32 + kk) * N + bx * BNp + nn];
  }
  __syncthreads();
  const size_t tile = ((size_t)bx * KT + by) * ((size_t)BNp * 32);
  for (int c = t; c < BNp * 4; c += 256) {
    const int nn = c >> 2, koct = (c & 3) * 8;
    __align__(16) bf16 h[8];
#pragma unroll
    for (int j = 0; j < 8; ++j) h[j] = (bf16)sLB[(koct + j) * LS + nn];
    *(i32x4*)(Bp + tile + (size_t)c * 8) = *(const i32x4*)h;
  }
}

// pack tw1 -> fp8 e4m3 tiles [nt 8][kw 291][n 128][k 64 B], values *32.
// Transpose-free: thread owns (n4 group, k8 group); 8 coalesced f32x4 loads,
// 4 x 8-B stores. No LDS, no barriers.
__device__ __forceinline__ void packTw1_dev(const float* __restrict__ tw1,
                                            u8* __restrict__ Bp, int nt, int kw) {
  const int t = threadIdx.x;
  const int n4 = t & 31, k8 = t >> 5;
  const int kbase = kw * 64 + k8 * 8;
  const int nbase = nt * 128 + n4 * 4;
  f32x4 v[8];
#pragma unroll
  for (int j = 0; j < 8; ++j) {
    const int gk = kbase + j;
    if (gk < 18592) {
      v[j] = *(const f32x4*)(tw1 + (size_t)gk * 1024 + nbase);
      v[j] *= 32.f;
    } else {
      v[j] = f32x4{0.f, 0.f, 0.f, 0.f};
    }
  }
  u8* tile = Bp + ((size_t)nt * 291 + kw) * 8192;
#pragma unroll
  for (int c = 0; c < 4; ++c) {
    int r0 = __builtin_amdgcn_cvt_pk_fp8_f32(v[0][c], v[1][c], 0, false);
    r0 = __builtin_amdgcn_cvt_pk_fp8_f32(v[2][c], v[3][c], r0, true);
    int r1 = __builtin_amdgcn_cvt_pk_fp8_f32(v[4][c], v[5][c], 0, false);
    r1 = __builtin_amdgcn_cvt_pk_fp8_f32(v[6][c], v[7][c], r1, true);
    i32x2 d; d[0] = r0; d[1] = r1;
    *(i32x2*)(tile + (n4 * 4 + c) * 64 + k8 * 8) = d;
  }
}

// ---------------------------------------------------------------- fused prologue
__global__ __launch_bounds__(256) void prologue_kernel(
    const float* __restrict__ xep, const float* __restrict__ xd,
    const float* __restrict__ pw1, const float* __restrict__ pw2,
    const float* __restrict__ bw1, const float* __restrict__ bw2,
    const float* __restrict__ tw1, const float* __restrict__ tw2,
    bf16* Xp, bf16* Xd, bf16* Bpw1, bf16* Bpw2, bf16* Bbw1, bf16* Bbw2,
    u8* Btw1, bf16* Btw2, u16* pairs, float* stats) {
  __shared__ float sLB[32 * 66];
  int i = blockIdx.x;
  if (i < 2328) { packTw1_dev(tw1, Btw1, i & 7, i >> 3); return; }
  i -= 2328;
  if (i < 1536) { packA_dev(xep, Xp, 768, i & 63, i >> 6); return; }
  i -= 1536;
  if (i < 512)  { packA_dev(xd, Xd, 256, i & 63, i >> 6); return; }
  i -= 512;
  if (i < 96)   { packB_dev(pw1, Bpw1, 768, 256, i & 3, i >> 2, sLB); return; }
  i -= 96;
  if (i < 8)    { packB_dev(pw2, Bpw2, 256, 64, 0, i, sLB); return; }
  i -= 8;
  if (i < 64)   { packB_dev(bw1, Bbw1, 256, 512, i & 7, i >> 3, sLB); return; }
  i -= 64;
  if (i < 16)   { packB_dev(bw2, Bbw2, 512, 64, 0, i, sLB); return; }
  i -= 16;
  if (i < 256)  { packB_dev(tw2, Btw2, 1024, 512, i & 7, i >> 3, sLB); return; }
  i -= 256;
  if (i == 0) pairs_dev(pairs, stats);
}

// embedding gather-sum -> cf[:,128:192], 8 rows per block
__device__ __forceinline__ void embed8_dev(const int* __restrict__ xs,
                                           const float* __restrict__ emb,
                                           float* __restrict__ cf, int blk) {
  const int wid = threadIdx.x >> 6, lane = threadIdx.x & 63;
#pragma unroll
  for (int s = 0; s < 2; ++s) {
    const int b = blk * 8 + s * 4 + wid;
    const int* row = xs + (size_t)b * 50;
    float acc = 0.f;
#pragma unroll 10
    for (int h = 0; h < 50; ++h) {
      int idx = row[h];
      acc += emb[(size_t)idx * 64 + lane];
    }
    cf[(size_t)b * 193 + 128 + lane] = acc;
  }
}

// ================================================================ bf16 MFMA GEMM body (small GEMMs)
// statsAcc: optional BN accumulation (pre-activation column sums/sumsq via
// wave shuffle-reduce + atomics) — used by proj2.
template <int BM, int BN, int MF, int NF>
__device__ __forceinline__ void gemm_body(
    const bf16* __restrict__ Ap, const bf16* __restrict__ Bp,
    const float* __restrict__ bias,
    float* __restrict__ outF, int ldF,
    bf16* __restrict__ outP, int ktN, int bmsh,
    int KT, int M0, int relu_flag, int bx, int by,
    bf16* sA, bf16* sB, float* statsAcc) {
  const int t = threadIdx.x;
  const int wid = t >> 6, lane = t & 63;
  const int wm = (wid >> 1) * (MF * 16);
  const int wn = (wid & 1) * (NF * 16);
  const int r16 = lane & 15, q = lane >> 4;

  f32x4 acc[MF][NF];
#pragma unroll
  for (int i = 0; i < MF; ++i)
#pragma unroll
    for (int j = 0; j < NF; ++j) acc[i][j] = f32x4{0.f, 0.f, 0.f, 0.f};

  const bf16* aBase = Ap + (size_t)bx * KT * (BM * 32);
  const bf16* bBase = Bp + (size_t)by * KT * (BN * 32);
  constexpr int A_CH = BM * 4;
  constexpr int B_CH = BN * 4;

  for (int kt = 0; kt < KT; ++kt) {
    const bf16* ag = aBase + (size_t)kt * (BM * 32);
    const bf16* bg = bBase + (size_t)kt * (BN * 32);
#pragma unroll
    for (int c = t; c < A_CH; c += 256) {
      const int row = c >> 2, qs = c & 3, qg = (qs - (row >> 1)) & 3;
      async16(sA + c * 8, ag + row * 32 + qg * 8);
    }
#pragma unroll
    for (int c = t; c < B_CH; c += 256) {
      const int row = c >> 2, qs = c & 3, qg = (qs - (row >> 1)) & 3;
      async16(sB + c * 8, bg + row * 32 + qg * 8);
    }
    __syncthreads();
    v8bf af[MF], bfr[NF];
#pragma unroll
    for (int i = 0; i < MF; ++i) {
      const int row = wm + i * 16 + r16;
      af[i] = *(const v8bf*)(sA + row * 32 + (((q + (row >> 1)) & 3) * 8));
    }
#pragma unroll
    for (int j = 0; j < NF; ++j) {
      const int row = wn + j * 16 + r16;
      bfr[j] = *(const v8bf*)(sB + row * 32 + (((q + (row >> 1)) & 3) * 8));
    }
#pragma unroll
    for (int i = 0; i < MF; ++i)
#pragma unroll
      for (int j = 0; j < NF; ++j)
        acc[i][j] = __builtin_amdgcn_mfma_f32_16x16x32_bf16(af[i], bfr[j], acc[i][j], 0, 0, 0);
    __syncthreads();
  }

  float cs[NF], cs2[NF];
#pragma unroll
  for (int j = 0; j < NF; ++j) { cs[j] = 0.f; cs2[j] = 0.f; }

#pragma unroll
  for (int j = 0; j < NF; ++j) {
    const int gn = by * BN + wn + j * 16 + r16;
    const float bv = bias[gn];
#pragma unroll
    for (int i = 0; i < MF; ++i) {
      const int gm0 = M0 + bx * BM + wm + i * 16 + q * 4;
#pragma unroll
      for (int r = 0; r < 4; ++r) {
        float v = acc[i][j][r] + bv;
        if (relu_flag) v = fmaxf(v, 0.f);
        if (statsAcc) { cs[j] += v; cs2[j] += v * v; }
        const int gm = gm0 + r;
        if (outF) outF[(size_t)gm * ldF + gn] = v;
        if (outP) {
          const int mt = gm >> bmsh, mm = gm & ((1 << bmsh) - 1);
          outP[(((size_t)mt * ktN + (gn >> 5)) << (bmsh + 5)) + ((size_t)mm << 5) + (gn & 31)] = (bf16)v;
        }
      }
    }
  }

  if (statsAcc) {
#pragma unroll
    for (int j = 0; j < NF; ++j) {
      float a = cs[j], b2 = cs2[j];
      a += __shfl_xor(a, 16, 64);  a += __shfl_xor(a, 32, 64);
      b2 += __shfl_xor(b2, 16, 64); b2 += __shfl_xor(b2, 32, 64);
      if (q == 0) {
        const int gn = by * BN + wn + j * 16 + r16;
        atomicAdd(&statsAcc[gn], a);
        atomicAdd(&statsAcc[64 + gn], b2);
      }
    }
  }
}

template <int BM, int BN, int MF, int NF>
__global__ __launch_bounds__(256, 2) void gemm_kernel(
    const bf16* __restrict__ Ap, const bf16* __restrict__ Bp,
    const float* __restrict__ bias,
    float* __restrict__ outF, int ldF,
    bf16* __restrict__ outP, int ktN, int bmsh,
    int KT, int M0, int relu_flag) {
  __shared__ __align__(16) bf16 sA[BM * 32];
  __shared__ __align__(16) bf16 sB[BN * 32];
  gemm_body<BM, BN, MF, NF>(Ap, Bp, bias, outF, ldF, outP, ktN, bmsh,
                            KT, M0, relu_flag, blockIdx.x, blockIdx.y, sA, sB, nullptr);
}

// two independent GEMMs (z=0,1) + optional embed slice (z=2)
template <int BM, int BN, int MF, int NF>
__global__ __launch_bounds__(256, 2) void gemm_dual_kernel(
    const bf16* Ap0, const bf16* Bp0, const float* bias0,
    float* outF0, int ldF0, bf16* outP0, int ktN0, int bmsh0, int KT0, int relu0, int gy0,
    float* statsAcc0,
    const bf16* Ap1, const bf16* Bp1, const float* bias1,
    float* outF1, int ldF1, bf16* outP1, int ktN1, int bmsh1, int KT1, int relu1, int gy1,
    const int* xs, const float* emb, float* cf) {
  __shared__ __align__(16) bf16 sA[BM * 32];
  __shared__ __align__(16) bf16 sB[BN * 32];
  if (blockIdx.z == 0) {
    if ((int)blockIdx.y >= gy0) return;
    gemm_body<BM, BN, MF, NF>(Ap0, Bp0, bias0, outF0, ldF0, outP0, ktN0, bmsh0,
                              KT0, 0, relu0, blockIdx.x, blockIdx.y, sA, sB, statsAcc0);
  } else if (blockIdx.z == 1) {
    if ((int)blockIdx.y >= gy1) return;
    gemm_body<BM, BN, MF, NF>(Ap1, Bp1, bias1, outF1, ldF1, outP1, ktN1, bmsh1,
                              KT1, 0, relu1, blockIdx.x, blockIdx.y, sA, sB, nullptr);
  } else {
    embed8_dev(xs, emb, cf, blockIdx.y * 64 + blockIdx.x);
  }
}

// ---------------------------------------------------------------- MX fp8 split-K GEMM -> bf16 partials [S][Mchunk][1024]
template <int S>
__global__ __launch_bounds__(256, 4) void gemm_splitk_mx(
    const u8* __restrict__ Ap, const u8* __restrict__ Bp,
    bf16* __restrict__ part, int Mchunk) {
  __shared__ __align__(16) u8 sAB[4][8192];   // [0..1]=A dbuf, [2..3]=B dbuf
  const int t = threadIdx.x;
  const int bx = blockIdx.x, by = blockIdx.y, bz = blockIdx.z;
  const int lane = t & 63, wid = t >> 6;
  const int wm = (wid >> 1) * 64, wn = (wid & 1) * 64;
  const int l31 = lane & 31, khalf = lane >> 5;
  const int kw0 = (291 * bz) / S, kw1 = (291 * (bz + 1)) / S;

  const int r1 = t >> 2;
  const int g1 = r1 * 64 + ((((t & 3) - (r1 >> 1)) & 3) << 4);
  const int r2 = (t + 256) >> 2;
  const int g2 = r2 * 64 + (((((t + 256) & 3) - (r2 >> 1)) & 3) << 4);
  u8* lA = &sAB[0][0] + t * 16;
  u8* lB = &sAB[2][0] + t * 16;

  const u8* fa0[2]; const u8* fa1[2]; const u8* fb0[2]; const u8* fb1[2];
#pragma unroll
  for (int i = 0; i < 2; ++i) {
    const int ra = wm + i * 32 + l31;
    const int qa = (khalf * 2 + (ra >> 1)) & 3;
    fa0[i] = &sAB[0][0] + ra * 64 + qa * 16;
    fa1[i] = &sAB[0][0] + ra * 64 + (((qa + 1) & 3) << 4);
    const int rb = wn + i * 32 + l31;
    const int qb = (khalf * 2 + (rb >> 1)) & 3;
    fb0[i] = &sAB[2][0] + rb * 64 + qb * 16;
    fb1[i] = &sAB[2][0] + rb * 64 + (((qb + 1) & 3) << 4);
  }

  f32x16 acc[2][2];
#pragma unroll
  for (int i = 0; i < 2; ++i)
#pragma unroll
    for (int j = 0; j < 2; ++j)
#pragma unroll
      for (int r = 0; r < 16; ++r) acc[i][j][r] = 0.f;

  const u8* agp = Ap + ((size_t)bx * 291 + kw0) * 8192;
  const u8* bgp = Bp + ((size_t)by * 291 + kw0) * 8192;

  auto compute = [&](int off) {
    v8i32 av[2], bv[2];
#pragma unroll
    for (int i = 0; i < 2; ++i) {
      union { i32x4 h[2]; v8i32 v; } ua;
      ua.h[0] = *(const i32x4*)(fa0[i] + off);
      ua.h[1] = *(const i32x4*)(fa1[i] + off);
      av[i] = ua.v;
      union { i32x4 h[2]; v8i32 v; } ub;
      ub.h[0] = *(const i32x4*)(fb0[i] + off);
      ub.h[1] = *(const i32x4*)(fb1[i] + off);
      bv[i] = ub.v;
    }
#pragma unroll
    for (int i = 0; i < 2; ++i)
#pragma unroll
      for (int j = 0; j < 2; ++j)
        acc[i][j] = __builtin_amdgcn_mfma_scale_f32_32x32x64_f8f6f4(
            av[i], bv[j], acc[i][j], 0, 0,
            0, 0x7F7F7F7F,   // A scale 2^0
            0, 0x7A7A7A7A);  // B scale 2^-5
  };

  const int nw = kw1 - kw0;
  int w = 0;
  for (; w + 2 <= nw; w += 2) {
    async16(lA, agp + g1);         async16(lA + 4096, agp + g2);
    async16(lB, bgp + g1);         async16(lB + 4096, bgp + g2);
    async16(lA + 8192, agp + 8192 + g1); async16(lA + 12288, agp + 8192 + g2);
    async16(lB + 8192, bgp + 8192 + g1); async16(lB + 12288, bgp + 8192 + g2);
    agp += 16384; bgp += 16384;
    __syncthreads();
    compute(0);
    compute(8192);
    __syncthreads();
  }
  if (w < nw) {
    async16(lA, agp + g1); async16(lA + 4096, agp + g2);
    async16(lB, bgp + g1); async16(lB + 4096, bgp + g2);
    __syncthreads();
    compute(0);
    __syncthreads();
  }

  bf16* pBase = part + (size_t)bz * Mchunk * 1024;
#pragma unroll
  for (int i = 0; i < 2; ++i)
#pragma unroll
    for (int j = 0; j < 2; ++j) {
      const int gn = by * 128 + wn + j * 32 + l31;
#pragma unroll
      for (int r = 0; r < 16; ++r) {
        const int gm = bx * 128 + wm + i * 32 + (r & 3) + 8 * (r >> 2) + 4 * khalf;
        pBase[(size_t)gm * 1024 + gn] = (bf16)acc[i][j][r];
      }
    }
}

// ---------------------------------------------------------------- split-K reduce -> t1 packed bf16 (BM=64)
__global__ __launch_bounds__(256) void reducek_kernel(const bf16* __restrict__ part,
                                                      const float* __restrict__ bias,
                                                      bf16* __restrict__ t1,
                                                      int S, int Mchunk, int M0) {
  const int idx = blockIdx.x * 256 + threadIdx.x;
  const int gm = idx >> 7;
  const int gn8 = (idx & 127) * 8;
  float v[8] = {0.f, 0.f, 0.f, 0.f, 0.f, 0.f, 0.f, 0.f};
  for (int s = 0; s < S; ++s) {
    v8bf p = *(const v8bf*)(part + ((size_t)s * Mchunk + gm) * 1024 + gn8);
#pragma unroll
    for (int r = 0; r < 8; ++r) v[r] += (float)p[r];
  }
  const f32x4 b0 = *(const f32x4*)(bias + gn8);
  const f32x4 b1 = *(const f32x4*)(bias + gn8 + 4);
  __align__(16) bf16 h[8];
#pragma unroll
  for (int r = 0; r < 4; ++r) h[r] = (bf16)fmaxf(v[r] + b0[r], 0.f);
#pragma unroll
  for (int r = 0; r < 4; ++r) h[4 + r] = (bf16)fmaxf(v[4 + r] + b1[r], 0.f);
  const int G = M0 + gm;
  const int mt = G >> 6, mm = G & 63, kt = gn8 >> 5;
  *(i32x4*)(t1 + (((size_t)mt * 32 + kt) << 11) + (mm << 5) + (gn8 & 31)) = *(const i32x4*)h;
}

// ---------------------------------------------------------------- interaction A -> fp8 tiles [mt][kw 291][128][64]
// BN fused: computes mu/rstd from atomic sums, normalizes z into cf cols 64:128,
// writes x_embed output slice (by==0), col 192 = 1.
__global__ __launch_bounds__(256, 2) void agen_kernel(const float* __restrict__ cf,
                                                      const float* __restrict__ z,
                                                      const float* __restrict__ gsum,
                                                      const float* __restrict__ gamma,
                                                      const float* __restrict__ beta,
                                                      const u16* __restrict__ pairs,
                                                      u8* __restrict__ Ap,
                                                      float* __restrict__ dout,
                                                      int rowBase) {
  __shared__ float sCF[64 * 193];
  __shared__ float sMu[64], sRstd[64];
  const int t = threadIdx.x;
  const int gRow0 = rowBase + blockIdx.x * 64;
  // bottom cols 0:64
  for (int idx = t; idx < 64 * 64; idx += 256) {
    const int r = idx >> 6, c = idx & 63;
    sCF[r * 193 + c] = cf[(size_t)(gRow0 + r) * 193 + c];
  }
  // embed cols 128:192
  for (int idx = t; idx < 64 * 64; idx += 256) {
    const int r = idx >> 6, c = idx & 63;
    sCF[r * 193 + 128 + c] = cf[(size_t)(gRow0 + r) * 193 + 128 + c];
  }
  if (t < 64) {
    const float mu = gsum[t] * (1.f / 4096.f);
    const float var = gsum[64 + t] * (1.f / 4096.f) - mu * mu;
    sMu[t] = mu;
    sRstd[t] = rsqrtf(var + 1e-5f);
    sCF[t * 193 + 192] = 1.f;
  }
  __syncthreads();
  // normalize z -> cols 64:128 (+ dout tail once)
  for (int idx = t; idx < 64 * 64; idx += 256) {
    const int r = idx >> 6, c = idx & 63;
    const float xe = gamma[c] * (z[(size_t)(gRow0 + r) * 64 + c] - sMu[c]) * sRstd[c] + beta[c];
    sCF[r * 193 + 64 + c] = xe;
    if (blockIdx.y == 0) dout[4096 + (size_t)(gRow0 + r) * 64 + c] = xe;
  }
  __syncthreads();

  const int kw0 = (291 * blockIdx.y) / 8;
  const int kw1 = (291 * (blockIdx.y + 1)) / 8;
  const int row = t >> 2, kq = t & 3;
  const int mt = blockIdx.x >> 1;
  const int mrow = (blockIdx.x & 1) * 64 + row;
  const float* myrow = sCF + row * 193;
  for (int kw = kw0; kw < kw1; ++kw) {
    const int kb = kw * 64 + kq * 16;
    i32x4 d;
    if (kb >= 18592) {
      d = i32x4{0, 0, 0, 0};
    } else {
      union { i32x4 v4[2]; u16 u[16]; } P;
      P.v4[0] = *(const i32x4*)(pairs + kb);
      P.v4[1] = *(const i32x4*)(pairs + kb + 8);
#pragma unroll
      for (int g = 0; g < 4; ++g) {
        float p[4];
#pragma unroll
        for (int j = 0; j < 4; ++j) {
          const u16 pr = P.u[g * 4 + j];
          p[j] = myrow[pr >> 8] * myrow[pr & 255];
        }
        int r = __builtin_amdgcn_cvt_pk_fp8_f32(p[0], p[1], 0, false);
        r = __builtin_amdgcn_cvt_pk_fp8_f32(p[2], p[3], r, true);
        d[g] = r;
      }
    }
    *(i32x4*)(Ap + (((size_t)mt * 291 + kw) * 128 + mrow) * 64 + kq * 16) = d;
  }
}

// ---------------------------------------------------------------- final dot (512->1) + sigmoid; t2 packed bf16 (BM=64, N=512)
__global__ __launch_bounds__(256) void topdot_kernel(const bf16* __restrict__ t2p,
                                                     const float* __restrict__ w,
                                                     const float* __restrict__ b3,
                                                     float* __restrict__ dout) {
  const int wid = threadIdx.x >> 6, lane = threadIdx.x & 63;
  const int b = blockIdx.x * 4 + wid;
  // lane covers n = lane*8 .. lane*8+7
  const size_t addr = ((((size_t)(b >> 6) * 16) + (lane >> 2)) << 11) +
                      ((size_t)(b & 63) << 5) + (lane & 3) * 8;
  v8bf p = *(const v8bf*)(t2p + addr);
  const float* wv = w + lane * 8;
  float s = 0.f;
#pragma unroll
  for (int r = 0; r < 8; ++r) s += (float)p[r] * wv[r];
  for (int m = 32; m > 0; m >>= 1) s += __shfl_xor(s, m, 64);
  if (lane == 0) dout[b] = 1.f / (1.f + __expf(-(s + b3[0])));
}

// ================================================================ launch
extern "C" void kernel_launch(void* const* d_in, const int* in_sizes, int n_in,
                              void* d_out, int out_size, void* d_ws, size_t ws_size,
                              hipStream_t stream) {
  const int*   xs   = (const int*)  d_in[0];
  const float* xd   = (const float*)d_in[1];
  const float* xep  = (const float*)d_in[2];
  const float* emb  = (const float*)d_in[3];
  const float* pw1  = (const float*)d_in[4];
  const float* pb1  = (const float*)d_in[5];
  const float* pw2  = (const float*)d_in[6];
  const float* pb2  = (const float*)d_in[7];
  const float* gmma = (const float*)d_in[8];
  const float* beta = (const float*)d_in[9];
  const float* bw1  = (const float*)d_in[10];
  const float* bb1  = (const float*)d_in[11];
  const float* bw2  = (const float*)d_in[12];
  const float* bb2  = (const float*)d_in[13];
  const float* tw1  = (const float*)d_in[14];
  const float* tb1  = (const float*)d_in[15];
  const float* tw2  = (const float*)d_in[16];
  const float* tb2  = (const float*)d_in[17];
  const float* tw3  = (const float*)d_in[18];
  const float* tb3  = (const float*)d_in[19];
  float* out = (float*)d_out;

  uint8_t* base = (uint8_t*)d_ws;
  size_t off = 0;
  auto alloc = [&](size_t b) {
    void* p = base + off;
    off = (off + b + 511) & ~((size_t)511);
    return p;
  };
  u16*  pairs = (u16*) alloc((size_t)18624 * 2);
  bf16* Xp    = (bf16*)alloc((size_t)4096 * 768 * 2);
  bf16* Xd    = (bf16*)alloc((size_t)4096 * 256 * 2);
  bf16* Bpw1  = (bf16*)alloc((size_t)768 * 256 * 2);
  bf16* Bpw2  = (bf16*)alloc((size_t)256 * 64 * 2);
  bf16* Bbw1  = (bf16*)alloc((size_t)256 * 512 * 2);
  bf16* Bbw2  = (bf16*)alloc((size_t)512 * 64 * 2);
  u8*   Btw1  = (u8*)  alloc((size_t)8 * 291 * 8192);
  bf16* Btw2  = (bf16*)alloc((size_t)1024 * 512 * 2);
  bf16* hbuf  = (bf16*)alloc((size_t)4096 * 256 * 2);
  float* z    = (float*)alloc((size_t)4096 * 64 * 4);
  float* stats= (float*)alloc((size_t)128 * 4);
  bf16* b0    = (bf16*)alloc((size_t)4096 * 512 * 2);
  float* cf   = (float*)alloc((size_t)4096 * 193 * 4);
  bf16* t1    = (bf16*)alloc((size_t)4096 * 1024 * 2);
  bf16* t2p   = (bf16*)alloc((size_t)4096 * 512 * 2);
  size_t fixedEnd = off;

  // pick (chunk, S): Ap fp8 = chunk*18624 B; partK bf16 = S*chunk*1024*2 B
  int chunk = 512, S = 8;
  {
    const int candC[5] = {4096, 2048, 2048, 1024, 512};
    const int candS[5] = {4, 8, 4, 8, 8};
    for (int i = 0; i < 5; ++i) {
      size_t need = fixedEnd + (size_t)candC[i] * 18624 + 1024 +
                    (size_t)candS[i] * candC[i] * 1024 * 2 + 1024;
      if (need <= ws_size) { chunk = candC[i]; S = candS[i]; break; }
    }
  }
  u8*   ApBig = (u8*)  alloc((size_t)chunk * 18624);
  bf16* partK = (bf16*)alloc((size_t)S * chunk * 1024 * 2);

  // ---- fused prologue (packs + pairs + stats zero) ----
  prologue_kernel<<<4817, 256, 0, stream>>>(
      xep, xd, pw1, pw2, bw1, bw2, tw1, tw2,
      Xp, Xd, Bpw1, Bpw2, Bbw1, Bbw2, Btw1, Btw2, pairs, stats);

  // ---- dual1: proj1 || bot1 || embed (z=2) ----
  gemm_dual_kernel<64, 64, 2, 2><<<dim3(64, 8, 3), 256, 0, stream>>>(
      Xp, Bpw1, pb1, nullptr, 0, hbuf, 8, 6, 24, 1, 4, nullptr,
      Xd, Bbw1, bb1, nullptr, 0, b0, 16, 6, 8, 1, 8,
      xs, emb, cf);
  // ---- dual2: proj2 (h@pw2 -> z f32 + BN stats atomics) || bot2 -> cf[:,0:64] ----
  gemm_dual_kernel<64, 64, 2, 2><<<dim3(64, 1, 2), 256, 0, stream>>>(
      hbuf, Bpw2, pb2, z, 64, nullptr, 0, 0, 8, 0, 1, stats,
      b0, Bbw2, bb2, cf, 193, nullptr, 0, 0, 16, 1, 1,
      nullptr, nullptr, nullptr);

  // ---- interaction (fp8, BN fused) + MX split-K GEMM + reduce ----
  for (int c0 = 0; c0 < 4096; c0 += chunk) {
    agen_kernel<<<dim3(chunk / 64, 8), 256, 0, stream>>>(
        cf, z, stats, gmma, beta, pairs, ApBig, out, c0);
    if (S == 4)
      gemm_splitk_mx<4><<<dim3(chunk / 128, 8, 4), 256, 0, stream>>>(
          ApBig, Btw1, partK, chunk);
    else
      gemm_splitk_mx<8><<<dim3(chunk / 128, 8, 8), 256, 0, stream>>>(
          ApBig, Btw1, partK, chunk);
    reducek_kernel<<<chunk / 2, 256, 0, stream>>>(partK, tb1, t1, S, chunk, c0);
  }

  // ---- top2: t2p = relu(t1@tw2+tb2) packed bf16 ----
  gemm_kernel<64, 64, 2, 2><<<dim3(64, 8), 256, 0, stream>>>(
      t1, Btw2, tb2, nullptr, 0, t2p, 16, 6, 32, 0, 1);
  // ---- top3: sigmoid(t2p@tw3+tb3) -> out[0:4096] ----
  topdot_kernel<<<1024, 256, 0, stream>>>(t2p, tw3, tb3, out);
}